// Round 1
// baseline (1414.925 us; speedup 1.0000x reference)
//
#include <hip/hip_runtime.h>
#include <math.h>

#define PI_D 3.14159265358979323846

constexpr int NBATCH = 8;
constexpr int NPTS   = 2048;
constexpr int F1C    = 100;
constexpr int F2C    = 100;

__host__ __device__ constexpr int S2c(int l){ return l*(2*l-1)*(2*l+1)/3; }

// ---- workspace layout (float offsets) ----
constexpr int OFF_WIN   = 0;                          // 60
constexpr int OFF_WMID  = OFF_WIN + 60;               // 32
constexpr int OFF_WOUTQ = OFF_WMID + 32;              // 20
constexpr int OFF_DM0W  = OFF_WOUTQ + 20;             // 60*256: [l:60*l^2][p][mm]
constexpr int OFF_DMID  = OFF_DM0W + 60*256;          // 32*S2c(16): [l:32*S2][p][mm][nn]
constexpr int OFF_DOUT  = OFF_DMID + 32*S2c(16);      // 20*S2c(10)
constexpr int OFF_DEQ   = OFF_DOUT + 20*S2c(10);      // S2c(16): [l:S2][mm][nn]
constexpr int OFF_IMG   = OFF_DEQ + S2c(16);          // 8*60*60
constexpr int OFF_XF    = OFF_IMG + NBATCH*60*60;     // 8*60*31*2
constexpr int OFF_XHAT  = OFF_XF + NBATCH*60*31*2;    // 8*256*2  [b][l*l+mm]
constexpr int OFF_WS2   = OFF_XHAT + NBATCH*256*2;    // 100*31*2 [o][ni]
constexpr int OFF_BN1   = OFF_WS2 + 100*31*2;         // 200 (sum,sumsq)
constexpr int OFF_BN1AB = OFF_BN1 + 200;              // 200 (sA,sB)
constexpr int OFF_BN2   = OFF_BN1AB + 200;            // 200
constexpr int OFF_BN2AB = OFF_BN2 + 200;              // 200
constexpr int OFF_WCONV = OFF_BN2AB + 200;            // 100*100*19*2 [i][o][ni]
constexpr int OFF_XHAT2 = OFF_WCONV + 100*100*19*2;   // 8*100*1330*2 [b][i][S2(l)+mm*tl+nn]
constexpr int OFF_SBUF  = OFF_XHAT2 + NBATCH*100*S2c(10)*2;
constexpr int OFF_ZHAT2 = OFF_SBUF + NBATCH*100*S2c(10)*2;
constexpr int OFF_Z2    = OFF_ZHAT2 + NBATCH*100*S2c(10)*2;  // 8*100*8000
constexpr int OFF_Z     = OFF_Z2 + NBATCH*100*20*20*20;      // 8*100*32768
constexpr int WS_TOTAL  = OFF_Z + NBATCH*100*32*32*32;       // ~39.7M floats

__device__ __forceinline__ int S2d(int l){ return l*(2*l-1)*(2*l+1)/3; }

// ---------- init: quadrature weights ----------
__global__ void k_quad(float* ws){
  int j = threadIdx.x;
  if (j < 60){
    double bb = 30.0, s = 0.0;
    for (int k = 0; k < 30; ++k) s += sin(PI_D*(2*j+1)*(2*k+1)/(4.0*bb))/(2*k+1);
    ws[OFF_WIN+j] = (float)(2.0/bb * sin(PI_D*(2*j+1)/(4.0*bb)) * s);
  }
  if (j < 32){
    double bb = 16.0, s = 0.0;
    for (int k = 0; k < 16; ++k) s += sin(PI_D*(2*j+1)*(2*k+1)/(4.0*bb))/(2*k+1);
    ws[OFF_WMID+j] = (float)(2.0/bb * sin(PI_D*(2*j+1)/(4.0*bb)) * s);
  }
  if (j < 20){
    double bb = 10.0, s = 0.0;
    for (int k = 0; k < 10; ++k) s += sin(PI_D*(2*j+1)*(2*k+1)/(4.0*bb))/(2*k+1);
    ws[OFF_WOUTQ+j] = (float)(2.0/bb * sin(PI_D*(2*j+1)/(4.0*bb)) * s);
  }
}

// ---------- init: Wigner-d tables ----------
__device__ double dfact(int n){ double r = 1.0; for (int i = 2; i <= n; ++i) r *= (double)i; return r; }

// d^l_{mp,m}(beta), standard convention (= exp(-i beta Jy) in |l,m> basis)
__device__ double dev_wigner(int l, int mp, int m, double beta){
  double ch = cos(0.5*beta), sh = sin(0.5*beta);
  int kmin = m - mp; if (kmin < 0) kmin = 0;
  int kmax = l + m; if (l - mp < kmax) kmax = l - mp;
  double pref = sqrt(dfact(l+mp)*dfact(l-mp)*dfact(l+m)*dfact(l-m));
  double sum = 0.0;
  for (int k = kmin; k <= kmax; ++k){
    double t = 1.0/(dfact(l+m-k)*dfact(k)*dfact(l-mp-k)*dfact(mp-m+k));
    if ((mp-m+k) & 1) t = -t;
    int ec = 2*l+m-mp-2*k, es = mp-m+2*k;
    double cp = 1.0; for (int e = 0; e < ec; ++e) cp *= ch;
    double sp = 1.0; for (int e = 0; e < es; ++e) sp *= sh;
    sum += t*cp*sp;
  }
  return pref*sum;
}

constexpr int N_DM0W = 60*256;
constexpr int N_DMID = 32*S2c(16);
constexpr int N_DOUT = 20*S2c(10);
constexpr int N_DEQ  = S2c(16);
constexpr int N_WIG  = N_DM0W + N_DMID + N_DOUT + N_DEQ;

__global__ void k_wigner(float* ws){
  int idx = blockIdx.x*blockDim.x + threadIdx.x;
  if (idx >= N_WIG) return;
  if (idx < N_DM0W){
    int l = 0; while (60*(l+1)*(l+1) <= idx) ++l;
    int rem = idx - 60*l*l, tl = 2*l+1;
    int p = rem/tl, mm = rem%tl;
    double beta = (p+0.5)*PI_D/60.0;
    ws[OFF_DM0W+idx] = (float)dev_wigner(l, mm-l, 0, beta) * ws[OFF_WIN+p];
    return;
  }
  idx -= N_DM0W;
  if (idx < N_DMID){
    int l = 0; while (32*S2d(l+1) <= idx) ++l;
    int rem = idx - 32*S2d(l), tl = 2*l+1;
    int q = rem % (tl*tl), p = rem/(tl*tl);
    int mm = q/tl, nn = q%tl;
    double beta = (p+0.5)*PI_D/32.0;
    ws[OFF_DMID + (idx + 32*S2d(l)) - 32*S2d(l)] = (float)dev_wigner(l, mm-l, nn-l, beta);
    return;
  }
  idx -= N_DMID;
  if (idx < N_DOUT){
    int l = 0; while (20*S2d(l+1) <= idx) ++l;
    int rem = idx - 20*S2d(l), tl = 2*l+1;
    int q = rem % (tl*tl), p = rem/(tl*tl);
    int mm = q/tl, nn = q%tl;
    double beta = (p+0.5)*PI_D/20.0;
    ws[OFF_DOUT+idx] = (float)dev_wigner(l, mm-l, nn-l, beta);
    return;
  }
  idx -= N_DOUT;
  {
    int l = 0; while (S2d(l+1) <= idx) ++l;
    int rem = idx - S2d(l), tl = 2*l+1;
    int mm = rem/tl, nn = rem%tl;
    ws[OFF_DEQ+idx] = (float)dev_wigner(l, mm-l, nn-l, 0.5*PI_D);
  }
}

// ---------- 1. point cloud -> sphere image (radial max projection) ----------
__global__ void k_project(const float* __restrict__ x, float* ws){
  int t = blockIdx.x*blockDim.x + threadIdx.x;
  if (t >= NBATCH*NPTS) return;
  int b = t / NPTS, n = t % NPTS;
  const float* xb = x + (size_t)b*3*NPTS;
  float xx = xb[n], yy = xb[NPTS+n], zz = xb[2*NPTS+n];
  float r = sqrtf(xx*xx + yy*yy + zz*zz + 1e-12f);
  float ct = zz / r;
  ct = fminf(fmaxf(ct, -1.0f + 1e-7f), 1.0f - 1e-7f);
  float beta = acosf(ct);
  float alpha = atan2f(yy, xx);
  if (alpha < 0.0f) alpha += 2.0f*(float)PI_D;
  int jb = (int)((beta / (float)PI_D) * 60.0f);
  jb = jb < 0 ? 0 : (jb > 59 ? 59 : jb);
  int ja = (int)((alpha / (2.0f*(float)PI_D)) * 60.0f);
  ja = ja < 0 ? 0 : (ja > 59 ? 59 : ja);
  unsigned* img = (unsigned*)(ws + OFF_IMG) + (b*3600 + jb*60 + ja);
  atomicMax(img, __float_as_uint(r));  // r > 0 always; positive float order = uint order
}

// ---------- 2. S2 DFT over alpha: XF[b][p][mi] = sum_a img*e^{-2pi i a m/60}, m=mi-15 ----------
__global__ void k_s2dft(float* ws){
  int t = blockIdx.x*blockDim.x + threadIdx.x;
  if (t >= NBATCH*60*31) return;
  int b = t/(60*31), r = t%(60*31);
  int p = r/31, mi = r%31, m = mi - 15;
  const float* img = ws + OFF_IMG + (b*60 + p)*60;
  float sr = 0.f, si = 0.f;
  for (int a = 0; a < 60; ++a){
    int k = ((a*m) % 60 + 60) % 60;
    float c = cospif(k/30.0f), s = sinpif(k/30.0f);   // e^{-2pi i k/60} = (c,-s)
    float v = img[a];
    sr += v*c; si -= v*s;
  }
  ws[OFF_XF + t*2]   = sr;
  ws[OFF_XF + t*2+1] = si;
}

// ---------- 3. xhat[b][l^2+mm] = sum_p dm0w[l][p][mm] * XF[b][p][m+15] ----------
__global__ void k_xhat(float* ws){
  int t = blockIdx.x*blockDim.x + threadIdx.x;
  if (t >= NBATCH*256) return;
  int b = t/256, flat = t%256;
  int l = 0; while ((l+1)*(l+1) <= flat) ++l;
  int mm = flat - l*l, tl = 2*l+1;
  int mi = mm - l + 15;
  float sr = 0.f, si = 0.f;
  for (int p = 0; p < 60; ++p){
    float w = ws[OFF_DM0W + 60*l*l + p*tl + mm];
    sr += w * ws[OFF_XF + ((b*60+p)*31 + mi)*2];
    si += w * ws[OFF_XF + ((b*60+p)*31 + mi)*2 + 1];
  }
  ws[OFF_XHAT + t*2]   = sr;
  ws[OFF_XHAT + t*2+1] = si;
}

// ---------- 3b. Ws2[o][ni] = sum_k w_s2[o][k]*scale * e^{+2pi i k n/60}, n=ni-15 ----------
__global__ void k_ws2(float* ws, const float* __restrict__ w_s2, float scale1){
  int t = blockIdx.x*blockDim.x + threadIdx.x;
  if (t >= 100*31) return;
  int o = t/31, ni = t%31, n = ni - 15;
  float sr = 0.f, si = 0.f;
  for (int k = 0; k < 60; ++k){
    int kk = ((k*n) % 60 + 60) % 60;
    float c = cospif(kk/30.0f), s = sinpif(kk/30.0f);
    float v = w_s2[o*60 + k] * scale1;
    sr += v*c; si += v*s;
  }
  ws[OFF_WS2 + t*2]   = sr;
  ws[OFF_WS2 + t*2+1] = si;
}

// ---------- 4. fused zhat-build + SO(3) IFFT (b=16) + bias + BN1 stats ----------
__global__ __launch_bounds__(256) void k_so3ifft_mid(float* ws, const float* __restrict__ b_s2){
  int bid = blockIdx.x;
  int p = bid & 31, bo = bid >> 5;
  int o = bo % F1C, b = bo / F1C;
  __shared__ float xh[512], Cc[512], Fg[1922], tmpS[1984];
  __shared__ float twr[32], twi[32], redA[4], redB[4];
  int tid = threadIdx.x;
  {
    int flat = tid;
    int l = 0; while ((l+1)*(l+1) <= flat) ++l;
    int mm = flat - l*l, tl = 2*l+1;
    xh[2*flat]   = ws[OFF_XHAT + (b*256+flat)*2];
    xh[2*flat+1] = ws[OFF_XHAT + (b*256+flat)*2+1];
    float deq0 = ws[OFF_DEQ + S2d(l) + mm*tl + l];   // d^l_{mm-l,0}(pi/2)
    int ni = mm - l + 15;
    float wr = ws[OFF_WS2 + (o*31+ni)*2], wi = ws[OFF_WS2 + (o*31+ni)*2+1];
    float f = (float)tl * deq0;
    Cc[2*flat] = f*wr; Cc[2*flat+1] = f*wi;
  }
  if (tid < 32){ float s, c; s = sinpif(tid/16.0f); c = cospif(tid/16.0f); twr[tid] = c; twi[tid] = s; } // e^{+2pi i tid/32}
  __syncthreads();
  // Fg[m,n] = sum_l d_mid[l][p][m][n] * (xh[l][m]*Cc[l][n])
  for (int q = tid; q < 961; q += 256){
    int mi = q/31, ni = q%31, m = mi-15, n = ni-15;
    int am = m < 0 ? -m : m, an = n < 0 ? -n : n;
    int lmin = am > an ? am : an;
    float ar = 0.f, ai = 0.f;
    for (int l = lmin; l < 16; ++l){
      int tl = 2*l+1;
      float d = ws[OFF_DMID + 32*S2d(l) + (p*tl + (m+l))*tl + (n+l)];
      int fa = l*l + (m+l), fc = l*l + (n+l);
      float xr = xh[2*fa], xi = xh[2*fa+1];
      float cr = Cc[2*fc], ci = Cc[2*fc+1];
      ar += d*(xr*cr - xi*ci);
      ai += d*(xr*ci + xi*cr);
    }
    Fg[2*q] = ar; Fg[2*q+1] = ai;
  }
  __syncthreads();
  // tmp[mi][g] = sum_n Fg[mi][n] e^{+2pi i n g/32}
  for (int q = tid; q < 992; q += 256){
    int mi = q/32, g = q%32;
    float ar = 0.f, ai = 0.f;
    for (int ni = 0; ni < 31; ++ni){
      int n = ni - 15;
      int k = (n*g) & 31;
      float c = twr[k], s = twi[k];
      float fr = Fg[2*(mi*31+ni)], fi = Fg[2*(mi*31+ni)+1];
      ar += fr*c - fi*s;
      ai += fr*s + fi*c;
    }
    tmpS[2*q] = ar; tmpS[2*q+1] = ai;
  }
  __syncthreads();
  float bsv = b_s2[o];
  float lsum = 0.f, lss = 0.f;
  float* z = ws + OFF_Z;
  for (int q = tid; q < 1024; q += 256){
    int a = q >> 5, g = q & 31;
    float vr = 0.f;
    for (int mi = 0; mi < 31; ++mi){
      int m = mi - 15;
      int k = (m*a) & 31;
      vr += tmpS[2*(mi*32+g)]*twr[k] - tmpS[2*(mi*32+g)+1]*twi[k];
    }
    float v = vr*(1.0f/1024.0f) + bsv;
    z[((size_t)(b*F1C+o)*32 + p)*1024 + q] = v;
    lsum += v; lss += v*v;
  }
  for (int off = 32; off; off >>= 1){ lsum += __shfl_down(lsum, off); lss += __shfl_down(lss, off); }
  if ((tid & 63) == 0){ redA[tid>>6] = lsum; redB[tid>>6] = lss; }
  __syncthreads();
  if (tid == 0){
    atomicAdd(&ws[OFF_BN1 + o],      redA[0]+redA[1]+redA[2]+redA[3]);
    atomicAdd(&ws[OFF_BN1 + 100 + o], redB[0]+redB[1]+redB[2]+redB[3]);
  }
}

__global__ void k_bnfin1(float* ws, const float* __restrict__ g1, const float* __restrict__ be1){
  int t = threadIdx.x;
  if (t >= 100) return;
  const float invN = 1.0f/262144.0f;   // 8*32*32*32
  float mu = ws[OFF_BN1+t]*invN;
  float var = ws[OFF_BN1+100+t]*invN - mu*mu;
  float sA = rsqrtf(var + 1e-5f) * g1[t];
  ws[OFF_BN1AB+t]     = sA;
  ws[OFF_BN1AB+100+t] = be1[t] - mu*sA;
}

// ---------- 6. fused BN1+ReLU + SO(3) forward FFT + Wigner projection -> xhat2 ----------
__global__ __launch_bounds__(256) void k_so3fft(float* ws){
  int bid = blockIdx.x;
  int o = bid % F1C, b = bid / F1C;
  __shared__ float y[1024], t1[1216], X2s[722], acc[2660], ds[1330];
  __shared__ float twr[32], twi[32];
  int tid = threadIdx.x;
  for (int q = tid; q < 2660; q += 256) acc[q] = 0.f;
  if (tid < 32){ twr[tid] = cospif(tid/16.0f); twi[tid] = sinpif(tid/16.0f); }
  float sA = ws[OFF_BN1AB+o], sB = ws[OFF_BN1AB+100+o];
  const float* z = ws + OFF_Z;
  __syncthreads();
  for (int p = 0; p < 32; ++p){
    float wm = ws[OFF_WMID+p];
    const float* zp = z + ((size_t)(b*F1C+o)*32 + p)*1024;
    for (int q = tid; q < 1024; q += 256){
      float v = zp[q]*sA + sB;
      y[q] = v > 0.f ? v : 0.f;
    }
    for (int q = tid; q < 1330; q += 256){
      int l = 0; while (S2d(l+1) <= q) ++l;
      int tl = 2*l+1;
      ds[q] = ws[OFF_DMID + 32*S2d(l) + p*tl*tl + (q - S2d(l))] * wm;
    }
    __syncthreads();
    // t1[a][ni] = sum_g y[a][g] e^{-2pi i g n/32}
    for (int q = tid; q < 608; q += 256){
      int a = q/19, ni = q%19, n = ni-9;
      float sr = 0.f, si = 0.f;
      for (int g = 0; g < 32; ++g){
        int k = (g*n) & 31;
        float v = y[a*32+g];
        sr += v*twr[k]; si -= v*twi[k];
      }
      t1[2*q] = sr; t1[2*q+1] = si;
    }
    __syncthreads();
    // X2s[mi][ni] = sum_a t1[a][ni] e^{-2pi i a m/32}
    for (int q = tid; q < 361; q += 256){
      int mi = q/19, ni = q%19, m = mi-9;
      float sr = 0.f, si = 0.f;
      for (int a = 0; a < 32; ++a){
        int k = (a*m) & 31;
        float c = twr[k], s = twi[k];
        float tr = t1[2*(a*19+ni)], ti = t1[2*(a*19+ni)+1];
        sr += tr*c + ti*s;
        si += ti*c - tr*s;
      }
      X2s[2*q] = sr; X2s[2*q+1] = si;
    }
    __syncthreads();
    for (int q = tid; q < 1330; q += 256){
      int l = 0; while (S2d(l+1) <= q) ++l;
      int loc = q - S2d(l), tl = 2*l+1;
      int mm = loc/tl, nn = loc%tl;
      int xi = (mm-l+9)*19 + (nn-l+9);
      float d = ds[q];
      acc[2*q]   += d * X2s[2*xi];
      acc[2*q+1] += d * X2s[2*xi+1];
    }
    __syncthreads();
  }
  for (int q = tid; q < 1330; q += 256){
    int base = OFF_XHAT2 + ((b*F1C+o)*1330 + q)*2;
    ws[base]   = acc[2*q];
    ws[base+1] = acc[2*q+1];
  }
}

// ---------- 7a. W[i][o][ni] = sum_j w_so3[i][o][j]*scale * e^{+2pi i j n/32} ----------
__global__ void k_wconv(float* ws, const float* __restrict__ w_so3, float scale2){
  int t = blockIdx.x*blockDim.x + threadIdx.x;
  if (t >= 100*100*19) return;
  int ni = t % 19, io = t / 19;
  int n = ni - 9;
  float sr = 0.f, si = 0.f;
  for (int j = 0; j < 32; ++j){
    int k = (j*n) & 31;
    float c = cospif(k/16.0f), s = sinpif(k/16.0f);
    float v = w_so3[io*32 + j] * scale2;
    sr += v*c; si += v*s;
  }
  ws[OFF_WCONV + t*2]   = sr;
  ws[OFF_WCONV + t*2+1] = si;
}

// ---------- 7b. S[b][i][l,mm,nn] = sum_k xhat2[b][i][l,mm,k] * d_eq[l][nn][k] ----------
__global__ void k_S(float* ws){
  int t = blockIdx.x*blockDim.x + threadIdx.x;
  if (t >= NBATCH*100*1330) return;
  int q = t % 1330, bi = t / 1330;
  int l = 0; while (S2d(l+1) <= q) ++l;
  int loc = q - S2d(l), tl = 2*l+1;
  int mm = loc/tl, nn = loc%tl;
  float sr = 0.f, si = 0.f;
  int xbase = OFF_XHAT2 + (bi*1330 + S2d(l) + mm*tl)*2;
  int dbase = OFF_DEQ + S2d(l) + nn*tl;
  for (int k = 0; k < tl; ++k){
    float d = ws[dbase + k];
    sr += d * ws[xbase + 2*k];
    si += d * ws[xbase + 2*k + 1];
  }
  ws[OFF_SBUF + t*2]   = sr;
  ws[OFF_SBUF + t*2+1] = si;
}

// ---------- 7c. zhat2[b][o][l,mm,nn] = sum_i S[b][i][l,mm,nn] * W[i][o][nn-l+9] ----------
__global__ void k_zhat2(float* ws){
  int t = blockIdx.x*blockDim.x + threadIdx.x;
  if (t >= NBATCH*100*1330) return;
  int q = t % 1330, bo = t / 1330;
  int o = bo % 100, b = bo / 100;
  int l = 0; while (S2d(l+1) <= q) ++l;
  int loc = q - S2d(l), tl = 2*l+1;
  int nn = loc % tl;
  int ni = nn - l + 9;
  float sr = 0.f, si = 0.f;
  for (int i = 0; i < 100; ++i){
    float Sr = ws[OFF_SBUF + ((b*100+i)*1330 + q)*2];
    float Si = ws[OFF_SBUF + ((b*100+i)*1330 + q)*2 + 1];
    float Wr = ws[OFF_WCONV + ((i*100+o)*19 + ni)*2];
    float Wi = ws[OFF_WCONV + ((i*100+o)*19 + ni)*2 + 1];
    sr += Sr*Wr - Si*Wi;
    si += Sr*Wi + Si*Wr;
  }
  ws[OFF_ZHAT2 + ((b*100+o)*1330 + q)*2]     = sr;
  ws[OFF_ZHAT2 + ((b*100+o)*1330 + q)*2 + 1] = si;
}

// ---------- 8. SO(3) IFFT (b=10) + bias + BN2 stats ----------
__global__ __launch_bounds__(256) void k_so3ifft_out(float* ws, const float* __restrict__ b_so3){
  int bid = blockIdx.x;
  int p = bid % 20, bo = bid / 20;
  int o = bo % F2C, b = bo / F2C;
  __shared__ float zh[2660], Fg[722], tmpS[760];
  __shared__ float twr[20], twi[20], redA[4], redB[4];
  int tid = threadIdx.x;
  for (int q = tid; q < 2660; q += 256) zh[q] = ws[OFF_ZHAT2 + (b*100+o)*2660 + q];
  if (tid < 20){ twr[tid] = cospif(tid/10.0f); twi[tid] = sinpif(tid/10.0f); }
  __syncthreads();
  for (int q = tid; q < 361; q += 256){
    int mi = q/19, ni = q%19, m = mi-9, n = ni-9;
    int am = m < 0 ? -m : m, an = n < 0 ? -n : n;
    int lmin = am > an ? am : an;
    float ar = 0.f, ai = 0.f;
    for (int l = lmin; l < 10; ++l){
      int tl = 2*l+1;
      float d = ws[OFF_DOUT + 20*S2d(l) + (p*tl + (m+l))*tl + (n+l)] * (float)tl;
      int fz = S2d(l) + (m+l)*tl + (n+l);
      ar += d*zh[2*fz]; ai += d*zh[2*fz+1];
    }
    Fg[2*q] = ar; Fg[2*q+1] = ai;
  }
  __syncthreads();
  for (int q = tid; q < 380; q += 256){
    int mi = q/20, g = q%20;
    float ar = 0.f, ai = 0.f;
    for (int ni = 0; ni < 19; ++ni){
      int n = ni - 9;
      int k = ((n*g) % 20 + 20) % 20;
      float c = twr[k], s = twi[k];
      float fr = Fg[2*(mi*19+ni)], fi = Fg[2*(mi*19+ni)+1];
      ar += fr*c - fi*s;
      ai += fr*s + fi*c;
    }
    tmpS[2*q] = ar; tmpS[2*q+1] = ai;
  }
  __syncthreads();
  float bsv = b_so3[o];
  float lsum = 0.f, lss = 0.f;
  float* z2 = ws + OFF_Z2;
  for (int q = tid; q < 400; q += 256){
    int a = q/20, g = q%20;
    float vr = 0.f;
    for (int mi = 0; mi < 19; ++mi){
      int m = mi - 9;
      int k = ((m*a) % 20 + 20) % 20;
      vr += tmpS[2*(mi*20+g)]*twr[k] - tmpS[2*(mi*20+g)+1]*twi[k];
    }
    float v = vr*(1.0f/400.0f) + bsv;
    z2[((b*100+o)*20 + p)*400 + q] = v;
    lsum += v; lss += v*v;
  }
  for (int off = 32; off; off >>= 1){ lsum += __shfl_down(lsum, off); lss += __shfl_down(lss, off); }
  if ((tid & 63) == 0){ redA[tid>>6] = lsum; redB[tid>>6] = lss; }
  __syncthreads();
  if (tid == 0){
    atomicAdd(&ws[OFF_BN2 + o],       redA[0]+redA[1]+redA[2]+redA[3]);
    atomicAdd(&ws[OFF_BN2 + 100 + o], redB[0]+redB[1]+redB[2]+redB[3]);
  }
}

__global__ void k_bnfin2(float* ws, const float* __restrict__ g2, const float* __restrict__ be2){
  int t = threadIdx.x;
  if (t >= 100) return;
  const float invN = 1.0f/64000.0f;  // 8*20*20*20
  float mu = ws[OFF_BN2+t]*invN;
  float var = ws[OFF_BN2+100+t]*invN - mu*mu;
  float sA = rsqrtf(var + 1e-5f) * g2[t];
  ws[OFF_BN2AB+t]     = sA;
  ws[OFF_BN2AB+100+t] = be2[t] - mu*sA;
}

// ---------- 9. out[b][c] = sum_{p,a,g} relu(z2*sA+sB) * w_outq[p] ----------
__global__ __launch_bounds__(256) void k_final(float* ws, float* __restrict__ out){
  int bid = blockIdx.x;
  int c = bid % 100, b = bid / 100;
  int tid = threadIdx.x;
  float sA = ws[OFF_BN2AB+c], sB = ws[OFF_BN2AB+100+c];
  const float* z2 = ws + OFF_Z2 + (size_t)(b*100+c)*8000;
  float lsum = 0.f;
  for (int q = tid; q < 8000; q += 256){
    int p = q / 400;
    float v = z2[q]*sA + sB;
    v = v > 0.f ? v : 0.f;
    lsum += v * ws[OFF_WOUTQ + p];
  }
  for (int off = 32; off; off >>= 1) lsum += __shfl_down(lsum, off);
  __shared__ float red[4];
  if ((tid & 63) == 0) red[tid>>6] = lsum;
  __syncthreads();
  if (tid == 0) out[b*100 + c] = red[0]+red[1]+red[2]+red[3];
}

extern "C" void kernel_launch(void* const* d_in, const int* in_sizes, int n_in,
                              void* d_out, int out_size, void* d_ws, size_t ws_size,
                              hipStream_t stream){
  const float* x      = (const float*)d_in[0];
  const float* w_s2   = (const float*)d_in[1];
  const float* b_s2   = (const float*)d_in[2];
  const float* g1     = (const float*)d_in[3];
  const float* be1    = (const float*)d_in[4];
  const float* w_so3  = (const float*)d_in[5];
  const float* b_so3  = (const float*)d_in[6];
  const float* g2     = (const float*)d_in[7];
  const float* be2    = (const float*)d_in[8];
  float* ws  = (float*)d_ws;
  float* out = (float*)d_out;

  hipMemsetAsync(ws + OFF_IMG, 0, NBATCH*3600*sizeof(float), stream);
  hipMemsetAsync(ws + OFF_BN1, 0, 200*sizeof(float), stream);
  hipMemsetAsync(ws + OFF_BN2, 0, 200*sizeof(float), stream);

  k_quad<<<1, 128, 0, stream>>>(ws);
  k_wigner<<<(N_WIG + 255)/256, 256, 0, stream>>>(ws);
  k_project<<<(NBATCH*NPTS + 255)/256, 256, 0, stream>>>(x, ws);
  k_s2dft<<<(NBATCH*60*31 + 255)/256, 256, 0, stream>>>(ws);
  k_xhat<<<(NBATCH*256 + 255)/256, 256, 0, stream>>>(ws);
  float scale1 = (float)(1.0/sqrt(60.0*1.0*65536.0/900.0));
  k_ws2<<<(100*31 + 255)/256, 256, 0, stream>>>(ws, w_s2, scale1);
  k_so3ifft_mid<<<NBATCH*F1C*32, 256, 0, stream>>>(ws, b_s2);
  k_bnfin1<<<1, 128, 0, stream>>>(ws, g1, be1);
  k_so3fft<<<NBATCH*F1C, 256, 0, stream>>>(ws);
  float scale2 = (float)(1.0/sqrt(32.0*100.0*1000.0/4096.0));
  k_wconv<<<(100*100*19 + 255)/256, 256, 0, stream>>>(ws, w_so3, scale2);
  k_S<<<(NBATCH*100*1330 + 255)/256, 256, 0, stream>>>(ws);
  k_zhat2<<<(NBATCH*100*1330 + 255)/256, 256, 0, stream>>>(ws);
  k_so3ifft_out<<<NBATCH*F2C*20, 256, 0, stream>>>(ws, b_so3);
  k_bnfin2<<<1, 128, 0, stream>>>(ws, g2, be2);
  k_final<<<NBATCH*100, 256, 0, stream>>>(ws, out);
}

// Round 2
// 1196.780 us; speedup vs baseline: 1.1823x; 1.1823x over previous
//
#include <hip/hip_runtime.h>
#include <math.h>

#define PI_D 3.14159265358979323846

constexpr int NBATCH = 8;
constexpr int NPTS   = 2048;
constexpr int F1C    = 100;
constexpr int F2C    = 100;

__host__ __device__ constexpr int S2c(int l){ return l*(2*l-1)*(2*l+1)/3; }

// ---- workspace layout (float offsets) ----
constexpr int OFF_WIN   = 0;                          // 60
constexpr int OFF_WMID  = OFF_WIN + 60;               // 32
constexpr int OFF_WOUTQ = OFF_WMID + 32;              // 20
constexpr int OFF_DM0W  = OFF_WOUTQ + 20;             // 60*256: [l:60*l^2][p][mm]
constexpr int OFF_DMID  = OFF_DM0W + 60*256;          // 32*S2c(16): [l:32*S2][p][mm][nn]
constexpr int OFF_DOUT  = OFF_DMID + 32*S2c(16);      // 20*S2c(10)
constexpr int OFF_DEQ   = OFF_DOUT + 20*S2c(10);      // S2c(16): [l:S2][mm][nn]
constexpr int OFF_IMG   = OFF_DEQ + S2c(16);          // 8*60*60
constexpr int OFF_XF    = OFF_IMG + NBATCH*60*60;     // 8*60*31*2
constexpr int OFF_XHAT  = OFF_XF + NBATCH*60*31*2;    // 8*256*2  [b][l*l+mm]
constexpr int OFF_WS2   = OFF_XHAT + NBATCH*256*2;    // 100*31*2 [o][ni]
constexpr int OFF_BN1   = OFF_WS2 + 100*31*2;         // 200 (sum,sumsq)
constexpr int OFF_BN1AB = OFF_BN1 + 200;              // 200 (sA,sB)
constexpr int OFF_BN2   = OFF_BN1AB + 200;            // 200
constexpr int OFF_BN2AB = OFF_BN2 + 200;              // 200
constexpr int OFF_LUTA  = OFF_BN2AB + 200;            // 1330 ints: dmid off (p=0)
constexpr int OFF_LUTB  = OFF_LUTA + 1330;            // 1330 ints: xi | tl2<<9
constexpr int OFF_WCONV = OFF_LUTB + 1330;            // 100*100*19*2 [i][o][ni]
constexpr int OFF_XHAT2 = OFF_WCONV + 100*100*19*2;   // 8*100*1330*2 [b][i][S2(l)+mm*tl+nn]
constexpr int OFF_SBUF  = OFF_XHAT2 + NBATCH*100*S2c(10)*2;
constexpr int OFF_ZHAT2 = OFF_SBUF + NBATCH*100*S2c(10)*2;
constexpr int OFF_Z2    = OFF_ZHAT2 + NBATCH*100*S2c(10)*2;  // 8*100*8000
constexpr int OFF_Z     = OFF_Z2 + NBATCH*100*20*20*20;      // 8*100*32768 (reused as X2W by k_so3fft_a)
constexpr int WS_TOTAL  = OFF_Z + NBATCH*100*32*32*32;

__device__ __forceinline__ int S2d(int l){ return l*(2*l-1)*(2*l+1)/3; }

// ---------- init: quadrature weights ----------
__global__ void k_quad(float* ws){
  int j = threadIdx.x;
  if (j < 60){
    double bb = 30.0, s = 0.0;
    for (int k = 0; k < 30; ++k) s += sin(PI_D*(2*j+1)*(2*k+1)/(4.0*bb))/(2*k+1);
    ws[OFF_WIN+j] = (float)(2.0/bb * sin(PI_D*(2*j+1)/(4.0*bb)) * s);
  }
  if (j < 32){
    double bb = 16.0, s = 0.0;
    for (int k = 0; k < 16; ++k) s += sin(PI_D*(2*j+1)*(2*k+1)/(4.0*bb))/(2*k+1);
    ws[OFF_WMID+j] = (float)(2.0/bb * sin(PI_D*(2*j+1)/(4.0*bb)) * s);
  }
  if (j < 20){
    double bb = 10.0, s = 0.0;
    for (int k = 0; k < 10; ++k) s += sin(PI_D*(2*j+1)*(2*k+1)/(4.0*bb))/(2*k+1);
    ws[OFF_WOUTQ+j] = (float)(2.0/bb * sin(PI_D*(2*j+1)/(4.0*bb)) * s);
  }
}

// ---------- init: LUT q -> (dmid offset, xi, tl^2) ----------
__global__ void k_lut(float* ws){
  int q = blockIdx.x*blockDim.x + threadIdx.x;
  if (q >= 1330) return;
  int l = 0; while (S2d(l+1) <= q) ++l;
  int loc = q - S2d(l), tl = 2*l+1;
  int mm = loc/tl, nn = loc%tl;
  ((int*)(ws+OFF_LUTA))[q] = 32*S2d(l) + mm*tl + nn;
  ((int*)(ws+OFF_LUTB))[q] = ((mm-l+9)*19 + (nn-l+9)) | ((tl*tl) << 9);
}

// ---------- init: Wigner-d tables ----------
__device__ double dfact(int n){ double r = 1.0; for (int i = 2; i <= n; ++i) r *= (double)i; return r; }

__device__ double dev_wigner(int l, int mp, int m, double beta){
  double ch = cos(0.5*beta), sh = sin(0.5*beta);
  int kmin = m - mp; if (kmin < 0) kmin = 0;
  int kmax = l + m; if (l - mp < kmax) kmax = l - mp;
  double pref = sqrt(dfact(l+mp)*dfact(l-mp)*dfact(l+m)*dfact(l-m));
  double sum = 0.0;
  for (int k = kmin; k <= kmax; ++k){
    double t = 1.0/(dfact(l+m-k)*dfact(k)*dfact(l-mp-k)*dfact(mp-m+k));
    if ((mp-m+k) & 1) t = -t;
    int ec = 2*l+m-mp-2*k, es = mp-m+2*k;
    double cp = 1.0; for (int e = 0; e < ec; ++e) cp *= ch;
    double sp = 1.0; for (int e = 0; e < es; ++e) sp *= sh;
    sum += t*cp*sp;
  }
  return pref*sum;
}

constexpr int N_DM0W = 60*256;
constexpr int N_DMID = 32*S2c(16);
constexpr int N_DOUT = 20*S2c(10);
constexpr int N_DEQ  = S2c(16);
constexpr int N_WIG  = N_DM0W + N_DMID + N_DOUT + N_DEQ;

__global__ void k_wigner(float* ws){
  int idx = blockIdx.x*blockDim.x + threadIdx.x;
  if (idx >= N_WIG) return;
  if (idx < N_DM0W){
    int l = 0; while (60*(l+1)*(l+1) <= idx) ++l;
    int rem = idx - 60*l*l, tl = 2*l+1;
    int p = rem/tl, mm = rem%tl;
    double beta = (p+0.5)*PI_D/60.0;
    ws[OFF_DM0W+idx] = (float)dev_wigner(l, mm-l, 0, beta) * ws[OFF_WIN+p];
    return;
  }
  idx -= N_DM0W;
  if (idx < N_DMID){
    int l = 0; while (32*S2d(l+1) <= idx) ++l;
    int rem = idx - 32*S2d(l), tl = 2*l+1;
    int q = rem % (tl*tl), p = rem/(tl*tl);
    int mm = q/tl, nn = q%tl;
    double beta = (p+0.5)*PI_D/32.0;
    ws[OFF_DMID+idx] = (float)dev_wigner(l, mm-l, nn-l, beta);
    return;
  }
  idx -= N_DMID;
  if (idx < N_DOUT){
    int l = 0; while (20*S2d(l+1) <= idx) ++l;
    int rem = idx - 20*S2d(l), tl = 2*l+1;
    int q = rem % (tl*tl), p = rem/(tl*tl);
    int mm = q/tl, nn = q%tl;
    double beta = (p+0.5)*PI_D/20.0;
    ws[OFF_DOUT+idx] = (float)dev_wigner(l, mm-l, nn-l, beta);
    return;
  }
  idx -= N_DOUT;
  {
    int l = 0; while (S2d(l+1) <= idx) ++l;
    int rem = idx - S2d(l), tl = 2*l+1;
    int mm = rem/tl, nn = rem%tl;
    ws[OFF_DEQ+idx] = (float)dev_wigner(l, mm-l, nn-l, 0.5*PI_D);
  }
}

// ---------- 1. point cloud -> sphere image (radial max projection) ----------
__global__ void k_project(const float* __restrict__ x, float* ws){
  int t = blockIdx.x*blockDim.x + threadIdx.x;
  if (t >= NBATCH*NPTS) return;
  int b = t / NPTS, n = t % NPTS;
  const float* xb = x + (size_t)b*3*NPTS;
  float xx = xb[n], yy = xb[NPTS+n], zz = xb[2*NPTS+n];
  float r = sqrtf(xx*xx + yy*yy + zz*zz + 1e-12f);
  float ct = zz / r;
  ct = fminf(fmaxf(ct, -1.0f + 1e-7f), 1.0f - 1e-7f);
  float beta = acosf(ct);
  float alpha = atan2f(yy, xx);
  if (alpha < 0.0f) alpha += 2.0f*(float)PI_D;
  int jb = (int)((beta / (float)PI_D) * 60.0f);
  jb = jb < 0 ? 0 : (jb > 59 ? 59 : jb);
  int ja = (int)((alpha / (2.0f*(float)PI_D)) * 60.0f);
  ja = ja < 0 ? 0 : (ja > 59 ? 59 : ja);
  unsigned* img = (unsigned*)(ws + OFF_IMG) + (b*3600 + jb*60 + ja);
  atomicMax(img, __float_as_uint(r));
}

// ---------- 2. S2 DFT over alpha ----------
__global__ void k_s2dft(float* ws){
  int t = blockIdx.x*blockDim.x + threadIdx.x;
  if (t >= NBATCH*60*31) return;
  int b = t/(60*31), r = t%(60*31);
  int p = r/31, mi = r%31, m = mi - 15;
  const float* img = ws + OFF_IMG + (b*60 + p)*60;
  float sr = 0.f, si = 0.f;
  for (int a = 0; a < 60; ++a){
    int k = ((a*m) % 60 + 60) % 60;
    float c = cospif(k/30.0f), s = sinpif(k/30.0f);
    float v = img[a];
    sr += v*c; si -= v*s;
  }
  ws[OFF_XF + t*2]   = sr;
  ws[OFF_XF + t*2+1] = si;
}

// ---------- 3. xhat ----------
__global__ void k_xhat(float* ws){
  int t = blockIdx.x*blockDim.x + threadIdx.x;
  if (t >= NBATCH*256) return;
  int b = t/256, flat = t%256;
  int l = 0; while ((l+1)*(l+1) <= flat) ++l;
  int mm = flat - l*l, tl = 2*l+1;
  int mi = mm - l + 15;
  float sr = 0.f, si = 0.f;
  for (int p = 0; p < 60; ++p){
    float w = ws[OFF_DM0W + 60*l*l + p*tl + mm];
    sr += w * ws[OFF_XF + ((b*60+p)*31 + mi)*2];
    si += w * ws[OFF_XF + ((b*60+p)*31 + mi)*2 + 1];
  }
  ws[OFF_XHAT + t*2]   = sr;
  ws[OFF_XHAT + t*2+1] = si;
}

// ---------- 3b. Ws2 ----------
__global__ void k_ws2(float* ws, const float* __restrict__ w_s2, float scale1){
  int t = blockIdx.x*blockDim.x + threadIdx.x;
  if (t >= 100*31) return;
  int o = t/31, ni = t%31, n = ni - 15;
  float sr = 0.f, si = 0.f;
  for (int k = 0; k < 60; ++k){
    int kk = ((k*n) % 60 + 60) % 60;
    float c = cospif(kk/30.0f), s = sinpif(kk/30.0f);
    float v = w_s2[o*60 + k] * scale1;
    sr += v*c; si += v*s;
  }
  ws[OFF_WS2 + t*2]   = sr;
  ws[OFF_WS2 + t*2+1] = si;
}

// ---------- 4. fused zhat-build + SO(3) IFFT (b=16) + bias + BN1 stats ----------
__global__ __launch_bounds__(256) void k_so3ifft_mid(float* ws, const float* __restrict__ b_s2){
  int bid = blockIdx.x;
  int p = bid & 31, bo = bid >> 5;
  int o = bo % F1C, b = bo / F1C;
  __shared__ float xh[512], Cc[512], Fg[1922], tmpS[1984];
  __shared__ float twr[32], twi[32], redA[4], redB[4];
  int tid = threadIdx.x;
  {
    int flat = tid;
    int l = 0; while ((l+1)*(l+1) <= flat) ++l;
    int mm = flat - l*l, tl = 2*l+1;
    xh[2*flat]   = ws[OFF_XHAT + (b*256+flat)*2];
    xh[2*flat+1] = ws[OFF_XHAT + (b*256+flat)*2+1];
    float deq0 = ws[OFF_DEQ + S2d(l) + mm*tl + l];
    int ni = mm - l + 15;
    float wr = ws[OFF_WS2 + (o*31+ni)*2], wi = ws[OFF_WS2 + (o*31+ni)*2+1];
    float f = (float)tl * deq0;
    Cc[2*flat] = f*wr; Cc[2*flat+1] = f*wi;
  }
  if (tid < 32){ float s, c; s = sinpif(tid/16.0f); c = cospif(tid/16.0f); twr[tid] = c; twi[tid] = s; }
  __syncthreads();
  for (int q = tid; q < 961; q += 256){
    int mi = q/31, ni = q%31, m = mi-15, n = ni-15;
    int am = m < 0 ? -m : m, an = n < 0 ? -n : n;
    int lmin = am > an ? am : an;
    float ar = 0.f, ai = 0.f;
    for (int l = lmin; l < 16; ++l){
      int tl = 2*l+1;
      float d = ws[OFF_DMID + 32*S2d(l) + (p*tl + (m+l))*tl + (n+l)];
      int fa = l*l + (m+l), fc = l*l + (n+l);
      float xr = xh[2*fa], xi = xh[2*fa+1];
      float cr = Cc[2*fc], ci = Cc[2*fc+1];
      ar += d*(xr*cr - xi*ci);
      ai += d*(xr*ci + xi*cr);
    }
    Fg[2*q] = ar; Fg[2*q+1] = ai;
  }
  __syncthreads();
  for (int q = tid; q < 992; q += 256){
    int mi = q/32, g = q%32;
    float ar = 0.f, ai = 0.f;
    for (int ni = 0; ni < 31; ++ni){
      int n = ni - 15;
      int k = (n*g) & 31;
      float c = twr[k], s = twi[k];
      float fr = Fg[2*(mi*31+ni)], fi = Fg[2*(mi*31+ni)+1];
      ar += fr*c - fi*s;
      ai += fr*s + fi*c;
    }
    tmpS[2*q] = ar; tmpS[2*q+1] = ai;
  }
  __syncthreads();
  float bsv = b_s2[o];
  float lsum = 0.f, lss = 0.f;
  float* z = ws + OFF_Z;
  for (int q = tid; q < 1024; q += 256){
    int a = q >> 5, g = q & 31;
    float vr = 0.f;
    for (int mi = 0; mi < 31; ++mi){
      int m = mi - 15;
      int k = (m*a) & 31;
      vr += tmpS[2*(mi*32+g)]*twr[k] - tmpS[2*(mi*32+g)+1]*twi[k];
    }
    float v = vr*(1.0f/1024.0f) + bsv;
    z[((size_t)(b*F1C+o)*32 + p)*1024 + q] = v;
    lsum += v; lss += v*v;
  }
  for (int off = 32; off; off >>= 1){ lsum += __shfl_down(lsum, off); lss += __shfl_down(lss, off); }
  if ((tid & 63) == 0){ redA[tid>>6] = lsum; redB[tid>>6] = lss; }
  __syncthreads();
  if (tid == 0){
    atomicAdd(&ws[OFF_BN1 + o],       redA[0]+redA[1]+redA[2]+redA[3]);
    atomicAdd(&ws[OFF_BN1 + 100 + o], redB[0]+redB[1]+redB[2]+redB[3]);
  }
}

__global__ void k_bnfin1(float* ws, const float* __restrict__ g1, const float* __restrict__ be1){
  int t = threadIdx.x;
  if (t >= 100) return;
  const float invN = 1.0f/262144.0f;
  float mu = ws[OFF_BN1+t]*invN;
  float var = ws[OFF_BN1+100+t]*invN - mu*mu;
  float sA = rsqrtf(var + 1e-5f) * g1[t];
  ws[OFF_BN1AB+t]     = sA;
  ws[OFF_BN1AB+100+t] = be1[t] - mu*sA;
}

// ---------- 6a. per-p slab: BN1+ReLU + 2D (gamma,alpha) DFT -> X2w (in place over z slice) ----------
__global__ __launch_bounds__(256) void k_so3fft_a(float* ws){
  int bid = blockIdx.x;                 // ((b*100+o)*32+p)
  int p = bid & 31, bo = bid >> 5;
  int o = bo % F1C;
  __shared__ float y[32*33];            // padded stride 33: no bank conflicts
  __shared__ float t1[1216];
  __shared__ float twr[32], twi[32];
  int tid = threadIdx.x;
  if (tid < 32){ twr[tid] = cospif(tid/16.0f); twi[tid] = sinpif(tid/16.0f); }
  float sA = ws[OFF_BN1AB+o], sB = ws[OFF_BN1AB+100+o];
  float* zp = ws + OFF_Z + (size_t)bid*1024;
  for (int q = tid; q < 1024; q += 256){
    float v = zp[q]*sA + sB;
    y[(q>>5)*33 + (q&31)] = v > 0.f ? v : 0.f;
  }
  __syncthreads();
  // t1[a][ni] = sum_g y[a][g] e^{-2pi i g n/32}
  for (int q = tid; q < 608; q += 256){
    int a = q/19, ni = q%19, n = ni-9;
    float sr = 0.f, si = 0.f;
    for (int g = 0; g < 32; ++g){
      int k = (g*n) & 31;
      float v = y[a*33+g];
      sr += v*twr[k]; si -= v*twi[k];
    }
    t1[2*q] = sr; t1[2*q+1] = si;
  }
  __syncthreads();
  // X2w[mi][ni] = wm * sum_a t1[a][ni] e^{-2pi i a m/32}  (written over own z slice)
  float wm = ws[OFF_WMID+p];
  for (int q = tid; q < 361; q += 256){
    int mi = q/19, ni = q%19, m = mi-9;
    float sr = 0.f, si = 0.f;
    for (int a = 0; a < 32; ++a){
      int k = (a*m) & 31;
      float c = twr[k], s = twi[k];
      float tr = t1[2*(a*19+ni)], ti = t1[2*(a*19+ni)+1];
      sr += tr*c + ti*s;
      si += ti*c - tr*s;
    }
    zp[2*q]   = sr*wm;
    zp[2*q+1] = si*wm;
  }
}

// ---------- 6b. Wigner beta-projection: xhat2[bo][q] = sum_p d_mid * X2w[p][xi] ----------
__global__ __launch_bounds__(256) void k_so3fft_b(float* ws){
  int bo = blockIdx.x;                  // b*100+o
  int tid = threadIdx.x;
  const float* xwbase = ws + OFF_Z + (size_t)bo*32*1024;
  const int* lutA = (const int*)(ws + OFF_LUTA);
  const int* lutB = (const int*)(ws + OFF_LUTB);
  for (int q = tid; q < 1330; q += 256){
    int la = lutA[q], lb = lutB[q];
    int xi = lb & 511, tl2 = lb >> 9;
    const float* dm = ws + OFF_DMID + la;
    float ar = 0.f, ai = 0.f;
    for (int pp = 0; pp < 32; ++pp){
      float d = dm[pp*tl2];
      const float* xw = xwbase + pp*1024 + 2*xi;
      ar += d*xw[0]; ai += d*xw[1];
    }
    int base = OFF_XHAT2 + (bo*1330 + q)*2;
    ws[base]   = ar;
    ws[base+1] = ai;
  }
}

// ---------- 7a. W[i][o][ni] ----------
__global__ void k_wconv(float* ws, const float* __restrict__ w_so3, float scale2){
  int t = blockIdx.x*blockDim.x + threadIdx.x;
  if (t >= 100*100*19) return;
  int ni = t % 19, io = t / 19;
  int n = ni - 9;
  float sr = 0.f, si = 0.f;
  for (int j = 0; j < 32; ++j){
    int k = (j*n) & 31;
    float c = cospif(k/16.0f), s = sinpif(k/16.0f);
    float v = w_so3[io*32 + j] * scale2;
    sr += v*c; si += v*s;
  }
  ws[OFF_WCONV + t*2]   = sr;
  ws[OFF_WCONV + t*2+1] = si;
}

// ---------- 7b. S = xhat2 . d_eq ----------
__global__ void k_S(float* ws){
  int t = blockIdx.x*blockDim.x + threadIdx.x;
  if (t >= NBATCH*100*1330) return;
  int q = t % 1330, bi = t / 1330;
  int l = 0; while (S2d(l+1) <= q) ++l;
  int loc = q - S2d(l), tl = 2*l+1;
  int mm = loc/tl, nn = loc%tl;
  float sr = 0.f, si = 0.f;
  int xbase = OFF_XHAT2 + (bi*1330 + S2d(l) + mm*tl)*2;
  int dbase = OFF_DEQ + S2d(l) + nn*tl;
  for (int k = 0; k < tl; ++k){
    float d = ws[dbase + k];
    sr += d * ws[xbase + 2*k];
    si += d * ws[xbase + 2*k + 1];
  }
  ws[OFF_SBUF + t*2]   = sr;
  ws[OFF_SBUF + t*2+1] = si;
}

// ---------- 7c. zhat2 = S . W over i ----------
__global__ void k_zhat2(float* ws){
  int t = blockIdx.x*blockDim.x + threadIdx.x;
  if (t >= NBATCH*100*1330) return;
  int q = t % 1330, bo = t / 1330;
  int o = bo % 100, b = bo / 100;
  int l = 0; while (S2d(l+1) <= q) ++l;
  int loc = q - S2d(l), tl = 2*l+1;
  int nn = loc % tl;
  int ni = nn - l + 9;
  float sr = 0.f, si = 0.f;
  for (int i = 0; i < 100; ++i){
    float Sr = ws[OFF_SBUF + ((b*100+i)*1330 + q)*2];
    float Si = ws[OFF_SBUF + ((b*100+i)*1330 + q)*2 + 1];
    float Wr = ws[OFF_WCONV + ((i*100+o)*19 + ni)*2];
    float Wi = ws[OFF_WCONV + ((i*100+o)*19 + ni)*2 + 1];
    sr += Sr*Wr - Si*Wi;
    si += Sr*Wi + Si*Wr;
  }
  ws[OFF_ZHAT2 + ((b*100+o)*1330 + q)*2]     = sr;
  ws[OFF_ZHAT2 + ((b*100+o)*1330 + q)*2 + 1] = si;
}

// ---------- 8. SO(3) IFFT (b=10) + bias + BN2 stats ----------
__global__ __launch_bounds__(256) void k_so3ifft_out(float* ws, const float* __restrict__ b_so3){
  int bid = blockIdx.x;
  int p = bid % 20, bo = bid / 20;
  int o = bo % F2C, b = bo / F2C;
  __shared__ float zh[2660], Fg[722], tmpS[760];
  __shared__ float twr[20], twi[20], redA[4], redB[4];
  int tid = threadIdx.x;
  for (int q = tid; q < 2660; q += 256) zh[q] = ws[OFF_ZHAT2 + (b*100+o)*2660 + q];
  if (tid < 20){ twr[tid] = cospif(tid/10.0f); twi[tid] = sinpif(tid/10.0f); }
  __syncthreads();
  for (int q = tid; q < 361; q += 256){
    int mi = q/19, ni = q%19, m = mi-9, n = ni-9;
    int am = m < 0 ? -m : m, an = n < 0 ? -n : n;
    int lmin = am > an ? am : an;
    float ar = 0.f, ai = 0.f;
    for (int l = lmin; l < 10; ++l){
      int tl = 2*l+1;
      float d = ws[OFF_DOUT + 20*S2d(l) + (p*tl + (m+l))*tl + (n+l)] * (float)tl;
      int fz = S2d(l) + (m+l)*tl + (n+l);
      ar += d*zh[2*fz]; ai += d*zh[2*fz+1];
    }
    Fg[2*q] = ar; Fg[2*q+1] = ai;
  }
  __syncthreads();
  for (int q = tid; q < 380; q += 256){
    int mi = q/20, g = q%20;
    float ar = 0.f, ai = 0.f;
    for (int ni = 0; ni < 19; ++ni){
      int n = ni - 9;
      int k = ((n*g) % 20 + 20) % 20;
      float c = twr[k], s = twi[k];
      float fr = Fg[2*(mi*19+ni)], fi = Fg[2*(mi*19+ni)+1];
      ar += fr*c - fi*s;
      ai += fr*s + fi*c;
    }
    tmpS[2*q] = ar; tmpS[2*q+1] = ai;
  }
  __syncthreads();
  float bsv = b_so3[o];
  float lsum = 0.f, lss = 0.f;
  float* z2 = ws + OFF_Z2;
  for (int q = tid; q < 400; q += 256){
    int a = q/20, g = q%20;
    float vr = 0.f;
    for (int mi = 0; mi < 19; ++mi){
      int m = mi - 9;
      int k = ((m*a) % 20 + 20) % 20;
      vr += tmpS[2*(mi*20+g)]*twr[k] - tmpS[2*(mi*20+g)+1]*twi[k];
    }
    float v = vr*(1.0f/400.0f) + bsv;
    z2[((b*100+o)*20 + p)*400 + q] = v;
    lsum += v; lss += v*v;
  }
  for (int off = 32; off; off >>= 1){ lsum += __shfl_down(lsum, off); lss += __shfl_down(lss, off); }
  if ((tid & 63) == 0){ redA[tid>>6] = lsum; redB[tid>>6] = lss; }
  __syncthreads();
  if (tid == 0){
    atomicAdd(&ws[OFF_BN2 + o],       redA[0]+redA[1]+redA[2]+redA[3]);
    atomicAdd(&ws[OFF_BN2 + 100 + o], redB[0]+redB[1]+redB[2]+redB[3]);
  }
}

__global__ void k_bnfin2(float* ws, const float* __restrict__ g2, const float* __restrict__ be2){
  int t = threadIdx.x;
  if (t >= 100) return;
  const float invN = 1.0f/64000.0f;
  float mu = ws[OFF_BN2+t]*invN;
  float var = ws[OFF_BN2+100+t]*invN - mu*mu;
  float sA = rsqrtf(var + 1e-5f) * g2[t];
  ws[OFF_BN2AB+t]     = sA;
  ws[OFF_BN2AB+100+t] = be2[t] - mu*sA;
}

// ---------- 9. final pooling ----------
__global__ __launch_bounds__(256) void k_final(float* ws, float* __restrict__ out){
  int bid = blockIdx.x;
  int c = bid % 100, b = bid / 100;
  int tid = threadIdx.x;
  float sA = ws[OFF_BN2AB+c], sB = ws[OFF_BN2AB+100+c];
  const float* z2 = ws + OFF_Z2 + (size_t)(b*100+c)*8000;
  float lsum = 0.f;
  for (int q = tid; q < 8000; q += 256){
    int p = q / 400;
    float v = z2[q]*sA + sB;
    v = v > 0.f ? v : 0.f;
    lsum += v * ws[OFF_WOUTQ + p];
  }
  for (int off = 32; off; off >>= 1) lsum += __shfl_down(lsum, off);
  __shared__ float red[4];
  if ((tid & 63) == 0) red[tid>>6] = lsum;
  __syncthreads();
  if (tid == 0) out[b*100 + c] = red[0]+red[1]+red[2]+red[3];
}

extern "C" void kernel_launch(void* const* d_in, const int* in_sizes, int n_in,
                              void* d_out, int out_size, void* d_ws, size_t ws_size,
                              hipStream_t stream){
  const float* x      = (const float*)d_in[0];
  const float* w_s2   = (const float*)d_in[1];
  const float* b_s2   = (const float*)d_in[2];
  const float* g1     = (const float*)d_in[3];
  const float* be1    = (const float*)d_in[4];
  const float* w_so3  = (const float*)d_in[5];
  const float* b_so3  = (const float*)d_in[6];
  const float* g2     = (const float*)d_in[7];
  const float* be2    = (const float*)d_in[8];
  float* ws  = (float*)d_ws;
  float* out = (float*)d_out;

  hipMemsetAsync(ws + OFF_IMG, 0, NBATCH*3600*sizeof(float), stream);
  hipMemsetAsync(ws + OFF_BN1, 0, 200*sizeof(float), stream);
  hipMemsetAsync(ws + OFF_BN2, 0, 200*sizeof(float), stream);

  k_quad<<<1, 128, 0, stream>>>(ws);
  k_lut<<<6, 256, 0, stream>>>(ws);
  k_wigner<<<(N_WIG + 255)/256, 256, 0, stream>>>(ws);
  k_project<<<(NBATCH*NPTS + 255)/256, 256, 0, stream>>>(x, ws);
  k_s2dft<<<(NBATCH*60*31 + 255)/256, 256, 0, stream>>>(ws);
  k_xhat<<<(NBATCH*256 + 255)/256, 256, 0, stream>>>(ws);
  float scale1 = (float)(1.0/sqrt(60.0*1.0*65536.0/900.0));
  k_ws2<<<(100*31 + 255)/256, 256, 0, stream>>>(ws, w_s2, scale1);
  k_so3ifft_mid<<<NBATCH*F1C*32, 256, 0, stream>>>(ws, b_s2);
  k_bnfin1<<<1, 128, 0, stream>>>(ws, g1, be1);
  k_so3fft_a<<<NBATCH*F1C*32, 256, 0, stream>>>(ws);
  k_so3fft_b<<<NBATCH*F1C, 256, 0, stream>>>(ws);
  float scale2 = (float)(1.0/sqrt(32.0*100.0*1000.0/4096.0));
  k_wconv<<<(100*100*19 + 255)/256, 256, 0, stream>>>(ws, w_so3, scale2);
  k_S<<<(NBATCH*100*1330 + 255)/256, 256, 0, stream>>>(ws);
  k_zhat2<<<(NBATCH*100*1330 + 255)/256, 256, 0, stream>>>(ws);
  k_so3ifft_out<<<NBATCH*F2C*20, 256, 0, stream>>>(ws, b_so3);
  k_bnfin2<<<1, 128, 0, stream>>>(ws, g2, be2);
  k_final<<<NBATCH*100, 256, 0, stream>>>(ws, out);
}

// Round 3
// 883.378 us; speedup vs baseline: 1.6017x; 1.3548x over previous
//
#include <hip/hip_runtime.h>
#include <math.h>

#define PI_D 3.14159265358979323846

constexpr int NBATCH = 8;
constexpr int NPTS   = 2048;
constexpr int F1C    = 100;
constexpr int F2C    = 100;

__host__ __device__ constexpr int S2c(int l){ return l*(2*l-1)*(2*l+1)/3; }

// ---- workspace layout (float offsets) ----
constexpr int OFF_WIN   = 0;                          // 60
constexpr int OFF_WMID  = OFF_WIN + 60;               // 32
constexpr int OFF_WOUTQ = OFF_WMID + 32;              // 20
constexpr int OFF_DM0W  = OFF_WOUTQ + 20;             // 60*256: [l:60*l^2][p][mm]
constexpr int OFF_DMID  = OFF_DM0W + 60*256;          // 32*S2c(16): [l:32*S2][p][mm][nn]
constexpr int OFF_DOUT  = OFF_DMID + 32*S2c(16);      // 20*S2c(10)
constexpr int OFF_DEQ   = OFF_DOUT + 20*S2c(10);      // S2c(16): [l:S2][mm][nn]
constexpr int OFF_IMG   = OFF_DEQ + S2c(16);          // 8*60*60
constexpr int OFF_XF    = OFF_IMG + NBATCH*60*60;     // 8*60*31*2
constexpr int OFF_XHAT  = OFF_XF + NBATCH*60*31*2;    // 8*256*2  [b][l*l+mm]
constexpr int OFF_WS2   = OFF_XHAT + NBATCH*256*2;    // 100*31*2 [o][ni]
constexpr int OFF_BN1   = OFF_WS2 + 100*31*2;         // 200 (sum,sumsq)
constexpr int OFF_BN1AB = OFF_BN1 + 200;              // 200 (sA,sB)
constexpr int OFF_BN2   = OFF_BN1AB + 200;            // 200
constexpr int OFF_BN2AB = OFF_BN2 + 200;              // 200
constexpr int OFF_LUTA  = OFF_BN2AB + 200;            // 1330 ints: dmid off (p=0)
constexpr int OFF_LUTB  = OFF_LUTA + 1330;            // 1330 ints: xi | tl2<<9
constexpr int OFF_WCONV = OFF_LUTB + 1330;            // 100*100*19*2 [i][o][ni]
constexpr int OFF_XHAT2 = OFF_WCONV + 100*100*19*2;   // 8*100*1330*2 [b][i][S2(l)+mm*tl+nn]
constexpr int OFF_SBUF  = OFF_XHAT2 + NBATCH*100*S2c(10)*2;
constexpr int OFF_ZHAT2 = OFF_SBUF + NBATCH*100*S2c(10)*2;
constexpr int OFF_Z2    = OFF_ZHAT2 + NBATCH*100*S2c(10)*2;  // 8*100*8000
constexpr int OFF_Z     = OFF_Z2 + NBATCH*100*20*20*20;      // 8*100*32768 (reused as X2W by k_so3fft_a)
constexpr int WS_TOTAL  = OFF_Z + NBATCH*100*32*32*32;

__device__ __forceinline__ int S2d(int l){ return l*(2*l-1)*(2*l+1)/3; }

// ---------- init: quadrature weights ----------
__global__ void k_quad(float* ws){
  int j = threadIdx.x;
  if (j < 60){
    double bb = 30.0, s = 0.0;
    for (int k = 0; k < 30; ++k) s += sin(PI_D*(2*j+1)*(2*k+1)/(4.0*bb))/(2*k+1);
    ws[OFF_WIN+j] = (float)(2.0/bb * sin(PI_D*(2*j+1)/(4.0*bb)) * s);
  }
  if (j < 32){
    double bb = 16.0, s = 0.0;
    for (int k = 0; k < 16; ++k) s += sin(PI_D*(2*j+1)*(2*k+1)/(4.0*bb))/(2*k+1);
    ws[OFF_WMID+j] = (float)(2.0/bb * sin(PI_D*(2*j+1)/(4.0*bb)) * s);
  }
  if (j < 20){
    double bb = 10.0, s = 0.0;
    for (int k = 0; k < 10; ++k) s += sin(PI_D*(2*j+1)*(2*k+1)/(4.0*bb))/(2*k+1);
    ws[OFF_WOUTQ+j] = (float)(2.0/bb * sin(PI_D*(2*j+1)/(4.0*bb)) * s);
  }
}

// ---------- init: LUT q -> (dmid offset, xi, tl^2) ----------
__global__ void k_lut(float* ws){
  int q = blockIdx.x*blockDim.x + threadIdx.x;
  if (q >= 1330) return;
  int l = 0; while (S2d(l+1) <= q) ++l;
  int loc = q - S2d(l), tl = 2*l+1;
  int mm = loc/tl, nn = loc%tl;
  ((int*)(ws+OFF_LUTA))[q] = 32*S2d(l) + mm*tl + nn;
  ((int*)(ws+OFF_LUTB))[q] = ((mm-l+9)*19 + (nn-l+9)) | ((tl*tl) << 9);
}

// ---------- init: Wigner-d tables ----------
__device__ double dfact(int n){ double r = 1.0; for (int i = 2; i <= n; ++i) r *= (double)i; return r; }

__device__ double dev_wigner(int l, int mp, int m, double beta){
  double ch = cos(0.5*beta), sh = sin(0.5*beta);
  int kmin = m - mp; if (kmin < 0) kmin = 0;
  int kmax = l + m; if (l - mp < kmax) kmax = l - mp;
  double pref = sqrt(dfact(l+mp)*dfact(l-mp)*dfact(l+m)*dfact(l-m));
  double sum = 0.0;
  for (int k = kmin; k <= kmax; ++k){
    double t = 1.0/(dfact(l+m-k)*dfact(k)*dfact(l-mp-k)*dfact(mp-m+k));
    if ((mp-m+k) & 1) t = -t;
    int ec = 2*l+m-mp-2*k, es = mp-m+2*k;
    double cp = 1.0; for (int e = 0; e < ec; ++e) cp *= ch;
    double sp = 1.0; for (int e = 0; e < es; ++e) sp *= sh;
    sum += t*cp*sp;
  }
  return pref*sum;
}

constexpr int N_DM0W = 60*256;
constexpr int N_DMID = 32*S2c(16);
constexpr int N_DOUT = 20*S2c(10);
constexpr int N_DEQ  = S2c(16);
constexpr int N_WIG  = N_DM0W + N_DMID + N_DOUT + N_DEQ;

__global__ void k_wigner(float* ws){
  int idx = blockIdx.x*blockDim.x + threadIdx.x;
  if (idx >= N_WIG) return;
  if (idx < N_DM0W){
    int l = 0; while (60*(l+1)*(l+1) <= idx) ++l;
    int rem = idx - 60*l*l, tl = 2*l+1;
    int p = rem/tl, mm = rem%tl;
    double beta = (p+0.5)*PI_D/60.0;
    ws[OFF_DM0W+idx] = (float)dev_wigner(l, mm-l, 0, beta) * ws[OFF_WIN+p];
    return;
  }
  idx -= N_DM0W;
  if (idx < N_DMID){
    int l = 0; while (32*S2d(l+1) <= idx) ++l;
    int rem = idx - 32*S2d(l), tl = 2*l+1;
    int q = rem % (tl*tl), p = rem/(tl*tl);
    int mm = q/tl, nn = q%tl;
    double beta = (p+0.5)*PI_D/32.0;
    ws[OFF_DMID+idx] = (float)dev_wigner(l, mm-l, nn-l, beta);
    return;
  }
  idx -= N_DMID;
  if (idx < N_DOUT){
    int l = 0; while (20*S2d(l+1) <= idx) ++l;
    int rem = idx - 20*S2d(l), tl = 2*l+1;
    int q = rem % (tl*tl), p = rem/(tl*tl);
    int mm = q/tl, nn = q%tl;
    double beta = (p+0.5)*PI_D/20.0;
    ws[OFF_DOUT+idx] = (float)dev_wigner(l, mm-l, nn-l, beta);
    return;
  }
  idx -= N_DOUT;
  {
    int l = 0; while (S2d(l+1) <= idx) ++l;
    int rem = idx - S2d(l), tl = 2*l+1;
    int mm = rem/tl, nn = rem%tl;
    ws[OFF_DEQ+idx] = (float)dev_wigner(l, mm-l, nn-l, 0.5*PI_D);
  }
}

// ---------- 1. point cloud -> sphere image ----------
__global__ void k_project(const float* __restrict__ x, float* ws){
  int t = blockIdx.x*blockDim.x + threadIdx.x;
  if (t >= NBATCH*NPTS) return;
  int b = t / NPTS, n = t % NPTS;
  const float* xb = x + (size_t)b*3*NPTS;
  float xx = xb[n], yy = xb[NPTS+n], zz = xb[2*NPTS+n];
  float r = sqrtf(xx*xx + yy*yy + zz*zz + 1e-12f);
  float ct = zz / r;
  ct = fminf(fmaxf(ct, -1.0f + 1e-7f), 1.0f - 1e-7f);
  float beta = acosf(ct);
  float alpha = atan2f(yy, xx);
  if (alpha < 0.0f) alpha += 2.0f*(float)PI_D;
  int jb = (int)((beta / (float)PI_D) * 60.0f);
  jb = jb < 0 ? 0 : (jb > 59 ? 59 : jb);
  int ja = (int)((alpha / (2.0f*(float)PI_D)) * 60.0f);
  ja = ja < 0 ? 0 : (ja > 59 ? 59 : ja);
  unsigned* img = (unsigned*)(ws + OFF_IMG) + (b*3600 + jb*60 + ja);
  atomicMax(img, __float_as_uint(r));
}

// ---------- 2. S2 DFT over alpha ----------
__global__ void k_s2dft(float* ws){
  int t = blockIdx.x*blockDim.x + threadIdx.x;
  if (t >= NBATCH*60*31) return;
  int b = t/(60*31), r = t%(60*31);
  int p = r/31, mi = r%31, m = mi - 15;
  const float* img = ws + OFF_IMG + (b*60 + p)*60;
  float sr = 0.f, si = 0.f;
  for (int a = 0; a < 60; ++a){
    int k = ((a*m) % 60 + 60) % 60;
    float c = cospif(k/30.0f), s = sinpif(k/30.0f);
    float v = img[a];
    sr += v*c; si -= v*s;
  }
  ws[OFF_XF + t*2]   = sr;
  ws[OFF_XF + t*2+1] = si;
}

// ---------- 3. xhat ----------
__global__ void k_xhat(float* ws){
  int t = blockIdx.x*blockDim.x + threadIdx.x;
  if (t >= NBATCH*256) return;
  int b = t/256, flat = t%256;
  int l = 0; while ((l+1)*(l+1) <= flat) ++l;
  int mm = flat - l*l, tl = 2*l+1;
  int mi = mm - l + 15;
  float sr = 0.f, si = 0.f;
  for (int p = 0; p < 60; ++p){
    float w = ws[OFF_DM0W + 60*l*l + p*tl + mm];
    sr += w * ws[OFF_XF + ((b*60+p)*31 + mi)*2];
    si += w * ws[OFF_XF + ((b*60+p)*31 + mi)*2 + 1];
  }
  ws[OFF_XHAT + t*2]   = sr;
  ws[OFF_XHAT + t*2+1] = si;
}

// ---------- 3b. Ws2 ----------
__global__ void k_ws2(float* ws, const float* __restrict__ w_s2, float scale1){
  int t = blockIdx.x*blockDim.x + threadIdx.x;
  if (t >= 100*31) return;
  int o = t/31, ni = t%31, n = ni - 15;
  float sr = 0.f, si = 0.f;
  for (int k = 0; k < 60; ++k){
    int kk = ((k*n) % 60 + 60) % 60;
    float c = cospif(kk/30.0f), s = sinpif(kk/30.0f);
    float v = w_s2[o*60 + k] * scale1;
    sr += v*c; si += v*s;
  }
  ws[OFF_WS2 + t*2]   = sr;
  ws[OFF_WS2 + t*2+1] = si;
}

// ---------- 4. fused zhat-build + SO(3) IFFT (b=16), Hermitian-halved ----------
__global__ __launch_bounds__(256) void k_so3ifft_mid(float* ws, const float* __restrict__ b_s2){
  int bid = blockIdx.x;
  int p = bid & 31, bo = bid >> 5;
  int o = bo % F1C, b = bo / F1C;
  __shared__ float xh[512], Cc[512], Fg[992], tmpS[1024];
  __shared__ float twr[32], twi[32], redA[4], redB[4];
  __shared__ int dbase[16];
  int tid = threadIdx.x;
  {
    int flat = tid;
    int l = 0; while ((l+1)*(l+1) <= flat) ++l;
    int mm = flat - l*l, tl = 2*l+1;
    xh[2*flat]   = ws[OFF_XHAT + (b*256+flat)*2];
    xh[2*flat+1] = ws[OFF_XHAT + (b*256+flat)*2+1];
    float deq0 = ws[OFF_DEQ + S2d(l) + mm*tl + l];
    int ni = mm - l + 15;
    float wr = ws[OFF_WS2 + (o*31+ni)*2], wi = ws[OFF_WS2 + (o*31+ni)*2+1];
    float f = (float)tl * deq0;
    Cc[2*flat] = f*wr; Cc[2*flat+1] = f*wi;
  }
  if (tid < 32){ twr[tid] = cospif(tid/16.0f); twi[tid] = sinpif(tid/16.0f); }
  if (tid < 16){ int l = tid, tl = 2*l+1; dbase[l] = OFF_DMID + 32*S2d(l) + p*tl*tl; }
  __syncthreads();
  // Fg[m][ni], m=0..15 only (Hermitian: Fg[-m,-n] = conj(Fg[m,n]))
  for (int q = tid; q < 496; q += 256){
    int m = q/31, ni = q%31, n = ni-15;
    int an = n < 0 ? -n : n;
    int lmin = m > an ? m : an;
    float ar = 0.f, ai = 0.f;
    for (int l = lmin; l < 16; ++l){
      int tl = 2*l+1;
      float d = ws[dbase[l] + (m+l)*tl + (n+l)];
      int fa = l*l + (m+l), fc = l*l + (n+l);
      float xr = xh[2*fa], xi = xh[2*fa+1];
      float cr = Cc[2*fc], ci = Cc[2*fc+1];
      ar += d*(xr*cr - xi*ci);
      ai += d*(xr*ci + xi*cr);
    }
    Fg[2*q] = ar; Fg[2*q+1] = ai;
  }
  __syncthreads();
  // tmp[m][g] = sum_n Fg[m][n] e^{+2pi i n g/32}, m=0..15
  for (int q = tid; q < 512; q += 256){
    int m = q>>5, g = q&31;
    float ar = 0.f, ai = 0.f;
    int base = 2*m*31;
    for (int ni = 0; ni < 31; ++ni){
      int k = ((ni-15)*g) & 31;
      float c = twr[k], s = twi[k];
      float fr = Fg[base+2*ni], fi = Fg[base+2*ni+1];
      ar += fr*c - fi*s;
      ai += fr*s + fi*c;
    }
    tmpS[2*q] = ar; tmpS[2*q+1] = ai;
  }
  __syncthreads();
  float bsv = b_s2[o];
  float lsum = 0.f, lss = 0.f;
  float* z = ws + OFF_Z;
  for (int q = tid; q < 1024; q += 256){
    int a = q >> 5, g = q & 31;
    float acc = 0.f;
    for (int m = 1; m < 16; ++m){
      int k = (m*a) & 31;
      acc += tmpS[2*(m*32+g)]*twr[k] - tmpS[2*(m*32+g)+1]*twi[k];
    }
    float vr = tmpS[2*g] + 2.0f*acc;   // m=0 once + 2*Re(m>0)
    float v = vr*(1.0f/1024.0f) + bsv;
    z[((size_t)(b*F1C+o)*32 + p)*1024 + q] = v;
    lsum += v; lss += v*v;
  }
  for (int off = 32; off; off >>= 1){ lsum += __shfl_down(lsum, off); lss += __shfl_down(lss, off); }
  if ((tid & 63) == 0){ redA[tid>>6] = lsum; redB[tid>>6] = lss; }
  __syncthreads();
  if (tid == 0){
    atomicAdd(&ws[OFF_BN1 + o],       redA[0]+redA[1]+redA[2]+redA[3]);
    atomicAdd(&ws[OFF_BN1 + 100 + o], redB[0]+redB[1]+redB[2]+redB[3]);
  }
}

__global__ void k_bnfin1(float* ws, const float* __restrict__ g1, const float* __restrict__ be1){
  int t = threadIdx.x;
  if (t >= 100) return;
  const float invN = 1.0f/262144.0f;
  float mu = ws[OFF_BN1+t]*invN;
  float var = ws[OFF_BN1+100+t]*invN - mu*mu;
  float sA = rsqrtf(var + 1e-5f) * g1[t];
  ws[OFF_BN1AB+t]     = sA;
  ws[OFF_BN1AB+100+t] = be1[t] - mu*sA;
}

// ---------- 6a. per-p slab: BN1+ReLU + 2D (gamma,alpha) DFT, alpha-half + mirror ----------
__global__ __launch_bounds__(256) void k_so3fft_a(float* ws){
  int bid = blockIdx.x;                 // ((b*100+o)*32+p)
  int p = bid & 31, bo = bid >> 5;
  int o = bo % F1C;
  __shared__ float y[32*33];
  __shared__ float t1[1216];
  __shared__ float twr[32], twi[32];
  int tid = threadIdx.x;
  if (tid < 32){ twr[tid] = cospif(tid/16.0f); twi[tid] = sinpif(tid/16.0f); }
  float sA = ws[OFF_BN1AB+o], sB = ws[OFF_BN1AB+100+o];
  float* zp = ws + OFF_Z + (size_t)bid*1024;
  for (int q = tid; q < 1024; q += 256){
    float v = zp[q]*sA + sB;
    y[(q>>5)*33 + (q&31)] = v > 0.f ? v : 0.f;
  }
  __syncthreads();
  // t1[a][ni] = sum_g y[a][g] e^{-2pi i g n/32}
  for (int q = tid; q < 608; q += 256){
    int a = q/19, ni = q%19, n = ni-9;
    float sr = 0.f, si = 0.f;
    for (int g = 0; g < 32; ++g){
      int k = (g*n) & 31;
      float v = y[a*33+g];
      sr += v*twr[k]; si -= v*twi[k];
    }
    t1[2*q] = sr; t1[2*q+1] = si;
  }
  __syncthreads();
  // X2w rows m=0..9 computed; m<0 mirrored: X2[-m,-n] = conj(X2[m,n])
  float wm = ws[OFF_WMID+p];
  for (int q = tid; q < 190; q += 256){
    int m = q/19, ni = q%19;
    float sr = 0.f, si = 0.f;
    for (int a = 0; a < 32; ++a){
      int k = (a*m) & 31;
      float c = twr[k], s = twi[k];
      float tr = t1[2*(a*19+ni)], ti = t1[2*(a*19+ni)+1];
      sr += tr*c + ti*s;
      si += ti*c - tr*s;
    }
    sr *= wm; si *= wm;
    int qf = (m+9)*19 + ni;
    zp[2*qf] = sr; zp[2*qf+1] = si;
    if (m > 0){
      int qm = (9-m)*19 + (18-ni);
      zp[2*qm] = sr; zp[2*qm+1] = -si;
    }
  }
}

// ---------- 6b. Wigner beta-projection ----------
__global__ __launch_bounds__(256) void k_so3fft_b(float* ws){
  int bo = blockIdx.x;
  int tid = threadIdx.x;
  const float* xwbase = ws + OFF_Z + (size_t)bo*32*1024;
  const int* lutA = (const int*)(ws + OFF_LUTA);
  const int* lutB = (const int*)(ws + OFF_LUTB);
  for (int q = tid; q < 1330; q += 256){
    int la = lutA[q], lb = lutB[q];
    int xi = lb & 511, tl2 = lb >> 9;
    const float* dm = ws + OFF_DMID + la;
    float ar = 0.f, ai = 0.f;
    for (int pp = 0; pp < 32; ++pp){
      float d = dm[pp*tl2];
      const float* xw = xwbase + pp*1024 + 2*xi;
      ar += d*xw[0]; ai += d*xw[1];
    }
    int base = OFF_XHAT2 + (bo*1330 + q)*2;
    ws[base]   = ar;
    ws[base+1] = ai;
  }
}

// ---------- 7a. W[i][o][ni] ----------
__global__ void k_wconv(float* ws, const float* __restrict__ w_so3, float scale2){
  int t = blockIdx.x*blockDim.x + threadIdx.x;
  if (t >= 100*100*19) return;
  int ni = t % 19, io = t / 19;
  int n = ni - 9;
  float sr = 0.f, si = 0.f;
  for (int j = 0; j < 32; ++j){
    int k = (j*n) & 31;
    float c = cospif(k/16.0f), s = sinpif(k/16.0f);
    float v = w_so3[io*32 + j] * scale2;
    sr += v*c; si += v*s;
  }
  ws[OFF_WCONV + t*2]   = sr;
  ws[OFF_WCONV + t*2+1] = si;
}

// ---------- 7b. S = xhat2 . d_eq ----------
__global__ void k_S(float* ws){
  int t = blockIdx.x*blockDim.x + threadIdx.x;
  if (t >= NBATCH*100*1330) return;
  int q = t % 1330, bi = t / 1330;
  int l = 0; while (S2d(l+1) <= q) ++l;
  int loc = q - S2d(l), tl = 2*l+1;
  int mm = loc/tl, nn = loc%tl;
  float sr = 0.f, si = 0.f;
  int xbase = OFF_XHAT2 + (bi*1330 + S2d(l) + mm*tl)*2;
  int dbase = OFF_DEQ + S2d(l) + nn*tl;
  for (int k = 0; k < tl; ++k){
    float d = ws[dbase + k];
    sr += d * ws[xbase + 2*k];
    si += d * ws[xbase + 2*k + 1];
  }
  ws[OFF_SBUF + t*2]   = sr;
  ws[OFF_SBUF + t*2+1] = si;
}

// ---------- 7c. zhat2 = S . W over i ----------
__global__ void k_zhat2(float* ws){
  int t = blockIdx.x*blockDim.x + threadIdx.x;
  if (t >= NBATCH*100*1330) return;
  int q = t % 1330, bo = t / 1330;
  int o = bo % 100, b = bo / 100;
  int l = 0; while (S2d(l+1) <= q) ++l;
  int loc = q - S2d(l), tl = 2*l+1;
  int nn = loc % tl;
  int ni = nn - l + 9;
  float sr = 0.f, si = 0.f;
  for (int i = 0; i < 100; ++i){
    float Sr = ws[OFF_SBUF + ((b*100+i)*1330 + q)*2];
    float Si = ws[OFF_SBUF + ((b*100+i)*1330 + q)*2 + 1];
    float Wr = ws[OFF_WCONV + ((i*100+o)*19 + ni)*2];
    float Wi = ws[OFF_WCONV + ((i*100+o)*19 + ni)*2 + 1];
    sr += Sr*Wr - Si*Wi;
    si += Sr*Wi + Si*Wr;
  }
  ws[OFF_ZHAT2 + ((b*100+o)*1330 + q)*2]     = sr;
  ws[OFF_ZHAT2 + ((b*100+o)*1330 + q)*2 + 1] = si;
}

// ---------- 8. SO(3) IFFT (b=10), Hermitian-halved + bias + BN2 stats ----------
__global__ __launch_bounds__(256) void k_so3ifft_out(float* ws, const float* __restrict__ b_so3){
  int bid = blockIdx.x;
  int p = bid % 20, bo = bid / 20;
  int o = bo % F2C, b = bo / F2C;
  __shared__ float zh[2660], Fg[380], tmpS[400];
  __shared__ float twr[20], twi[20], redA[4], redB[4];
  int tid = threadIdx.x;
  for (int q = tid; q < 2660; q += 256) zh[q] = ws[OFF_ZHAT2 + (b*100+o)*2660 + q];
  if (tid < 20){ twr[tid] = cospif(tid/10.0f); twi[tid] = sinpif(tid/10.0f); }
  __syncthreads();
  // Fg[m][ni], m=0..9 (Hermitian)
  for (int q = tid; q < 190; q += 256){
    int m = q/19, ni = q%19, n = ni-9;
    int an = n < 0 ? -n : n;
    int lmin = m > an ? m : an;
    float ar = 0.f, ai = 0.f;
    for (int l = lmin; l < 10; ++l){
      int tl = 2*l+1;
      float d = ws[OFF_DOUT + 20*S2d(l) + (p*tl + (m+l))*tl + (n+l)] * (float)tl;
      int fz = S2d(l) + (m+l)*tl + (n+l);
      ar += d*zh[2*fz]; ai += d*zh[2*fz+1];
    }
    Fg[2*q] = ar; Fg[2*q+1] = ai;
  }
  __syncthreads();
  // tmp[m][g], m=0..9
  for (int q = tid; q < 200; q += 256){
    int m = q/20, g = q%20;
    float ar = 0.f, ai = 0.f;
    for (int ni = 0; ni < 19; ++ni){
      int n = ni - 9;
      int k = ((n*g) % 20 + 20) % 20;
      float c = twr[k], s = twi[k];
      float fr = Fg[2*(m*19+ni)], fi = Fg[2*(m*19+ni)+1];
      ar += fr*c - fi*s;
      ai += fr*s + fi*c;
    }
    tmpS[2*q] = ar; tmpS[2*q+1] = ai;
  }
  __syncthreads();
  float bsv = b_so3[o];
  float lsum = 0.f, lss = 0.f;
  float* z2 = ws + OFF_Z2;
  for (int q = tid; q < 400; q += 256){
    int a = q/20, g = q%20;
    float acc = 0.f;
    for (int m = 1; m < 10; ++m){
      int k = (m*a) % 20;
      acc += tmpS[2*(m*20+g)]*twr[k] - tmpS[2*(m*20+g)+1]*twi[k];
    }
    float vr = tmpS[2*g] + 2.0f*acc;
    float v = vr*(1.0f/400.0f) + bsv;
    z2[((b*100+o)*20 + p)*400 + q] = v;
    lsum += v; lss += v*v;
  }
  for (int off = 32; off; off >>= 1){ lsum += __shfl_down(lsum, off); lss += __shfl_down(lss, off); }
  if ((tid & 63) == 0){ redA[tid>>6] = lsum; redB[tid>>6] = lss; }
  __syncthreads();
  if (tid == 0){
    atomicAdd(&ws[OFF_BN2 + o],       redA[0]+redA[1]+redA[2]+redA[3]);
    atomicAdd(&ws[OFF_BN2 + 100 + o], redB[0]+redB[1]+redB[2]+redB[3]);
  }
}

__global__ void k_bnfin2(float* ws, const float* __restrict__ g2, const float* __restrict__ be2){
  int t = threadIdx.x;
  if (t >= 100) return;
  const float invN = 1.0f/64000.0f;
  float mu = ws[OFF_BN2+t]*invN;
  float var = ws[OFF_BN2+100+t]*invN - mu*mu;
  float sA = rsqrtf(var + 1e-5f) * g2[t];
  ws[OFF_BN2AB+t]     = sA;
  ws[OFF_BN2AB+100+t] = be2[t] - mu*sA;
}

// ---------- 9. final pooling ----------
__global__ __launch_bounds__(256) void k_final(float* ws, float* __restrict__ out){
  int bid = blockIdx.x;
  int c = bid % 100, b = bid / 100;
  int tid = threadIdx.x;
  float sA = ws[OFF_BN2AB+c], sB = ws[OFF_BN2AB+100+c];
  const float* z2 = ws + OFF_Z2 + (size_t)(b*100+c)*8000;
  float lsum = 0.f;
  for (int q = tid; q < 8000; q += 256){
    int p = q / 400;
    float v = z2[q]*sA + sB;
    v = v > 0.f ? v : 0.f;
    lsum += v * ws[OFF_WOUTQ + p];
  }
  for (int off = 32; off; off >>= 1) lsum += __shfl_down(lsum, off);
  __shared__ float red[4];
  if ((tid & 63) == 0) red[tid>>6] = lsum;
  __syncthreads();
  if (tid == 0) out[b*100 + c] = red[0]+red[1]+red[2]+red[3];
}

extern "C" void kernel_launch(void* const* d_in, const int* in_sizes, int n_in,
                              void* d_out, int out_size, void* d_ws, size_t ws_size,
                              hipStream_t stream){
  const float* x      = (const float*)d_in[0];
  const float* w_s2   = (const float*)d_in[1];
  const float* b_s2   = (const float*)d_in[2];
  const float* g1     = (const float*)d_in[3];
  const float* be1    = (const float*)d_in[4];
  const float* w_so3  = (const float*)d_in[5];
  const float* b_so3  = (const float*)d_in[6];
  const float* g2     = (const float*)d_in[7];
  const float* be2    = (const float*)d_in[8];
  float* ws  = (float*)d_ws;
  float* out = (float*)d_out;

  hipMemsetAsync(ws + OFF_IMG, 0, NBATCH*3600*sizeof(float), stream);
  hipMemsetAsync(ws + OFF_BN1, 0, 200*sizeof(float), stream);
  hipMemsetAsync(ws + OFF_BN2, 0, 200*sizeof(float), stream);

  k_quad<<<1, 128, 0, stream>>>(ws);
  k_lut<<<6, 256, 0, stream>>>(ws);
  k_wigner<<<(N_WIG + 255)/256, 256, 0, stream>>>(ws);
  k_project<<<(NBATCH*NPTS + 255)/256, 256, 0, stream>>>(x, ws);
  k_s2dft<<<(NBATCH*60*31 + 255)/256, 256, 0, stream>>>(ws);
  k_xhat<<<(NBATCH*256 + 255)/256, 256, 0, stream>>>(ws);
  float scale1 = (float)(1.0/sqrt(60.0*1.0*65536.0/900.0));
  k_ws2<<<(100*31 + 255)/256, 256, 0, stream>>>(ws, w_s2, scale1);
  k_so3ifft_mid<<<NBATCH*F1C*32, 256, 0, stream>>>(ws, b_s2);
  k_bnfin1<<<1, 128, 0, stream>>>(ws, g1, be1);
  k_so3fft_a<<<NBATCH*F1C*32, 256, 0, stream>>>(ws);
  k_so3fft_b<<<NBATCH*F1C, 256, 0, stream>>>(ws);
  float scale2 = (float)(1.0/sqrt(32.0*100.0*1000.0/4096.0));
  k_wconv<<<(100*100*19 + 255)/256, 256, 0, stream>>>(ws, w_so3, scale2);
  k_S<<<(NBATCH*100*1330 + 255)/256, 256, 0, stream>>>(ws);
  k_zhat2<<<(NBATCH*100*1330 + 255)/256, 256, 0, stream>>>(ws);
  k_so3ifft_out<<<NBATCH*F2C*20, 256, 0, stream>>>(ws, b_so3);
  k_bnfin2<<<1, 128, 0, stream>>>(ws, g2, be2);
  k_final<<<NBATCH*100, 256, 0, stream>>>(ws, out);
}

// Round 4
// 695.174 us; speedup vs baseline: 2.0354x; 1.2707x over previous
//
#include <hip/hip_runtime.h>
#include <math.h>

#define PI_D 3.14159265358979323846

constexpr int NBATCH = 8;
constexpr int NPTS   = 2048;
constexpr int F1C    = 100;
constexpr int F2C    = 100;

__host__ __device__ constexpr int S2c(int l){ return l*(2*l-1)*(2*l+1)/3; }

// ---- workspace layout (float offsets) ----
constexpr int OFF_WIN   = 0;                          // 60
constexpr int OFF_WMID  = OFF_WIN + 60;               // 32
constexpr int OFF_WOUTQ = OFF_WMID + 32;              // 20
constexpr int OFF_DM0W  = OFF_WOUTQ + 20;             // 60*256
constexpr int OFF_DMID  = OFF_DM0W + 60*256;          // 32*S2c(16)
constexpr int OFF_DOUT  = OFF_DMID + 32*S2c(16);      // 20*S2c(10)
constexpr int OFF_DEQ   = OFF_DOUT + 20*S2c(10);      // S2c(16)
constexpr int OFF_IMG   = OFF_DEQ + S2c(16);          // 8*60*60
constexpr int OFF_XF    = OFF_IMG + NBATCH*60*60;     // 8*60*31*2
constexpr int OFF_XHAT  = OFF_XF + NBATCH*60*31*2;    // 8*256*2
constexpr int OFF_WS2   = OFF_XHAT + NBATCH*256*2;    // 100*31*2
constexpr int OFF_BN1   = OFF_WS2 + 100*31*2;         // 200
constexpr int OFF_BN1AB = OFF_BN1 + 200;              // 200
constexpr int OFF_BN2   = OFF_BN1AB + 200;            // 200
constexpr int OFF_BN2AB = OFF_BN2 + 200;              // 200
constexpr int OFF_LUTA  = OFF_BN2AB + 200;            // 1330 ints
constexpr int OFF_LUTB  = OFF_LUTA + 1330;            // 1330 ints
constexpr int OFF_WCONV = OFF_LUTB + 1330;            // 100*100*19*2
constexpr int OFF_XHAT2 = OFF_WCONV + 100*100*19*2;   // 8*100*1330*2
constexpr int OFF_SBUF  = OFF_XHAT2 + NBATCH*100*S2c(10)*2;
constexpr int OFF_ZHAT2 = OFF_SBUF + NBATCH*100*S2c(10)*2;
constexpr int OFF_Z2    = OFF_ZHAT2 + NBATCH*100*S2c(10)*2;  // 8*100*8000
constexpr int OFF_Z     = OFF_Z2 + NBATCH*100*20*20*20;      // 8*100*32768
constexpr int WS_TOTAL  = OFF_Z + NBATCH*100*32*32*32;

__device__ __forceinline__ int S2d(int l){ return l*(2*l-1)*(2*l+1)/3; }

// ---------- init: quadrature weights ----------
__global__ void k_quad(float* ws){
  int j = threadIdx.x;
  if (j < 60){
    double bb = 30.0, s = 0.0;
    for (int k = 0; k < 30; ++k) s += sin(PI_D*(2*j+1)*(2*k+1)/(4.0*bb))/(2*k+1);
    ws[OFF_WIN+j] = (float)(2.0/bb * sin(PI_D*(2*j+1)/(4.0*bb)) * s);
  }
  if (j < 32){
    double bb = 16.0, s = 0.0;
    for (int k = 0; k < 16; ++k) s += sin(PI_D*(2*j+1)*(2*k+1)/(4.0*bb))/(2*k+1);
    ws[OFF_WMID+j] = (float)(2.0/bb * sin(PI_D*(2*j+1)/(4.0*bb)) * s);
  }
  if (j < 20){
    double bb = 10.0, s = 0.0;
    for (int k = 0; k < 10; ++k) s += sin(PI_D*(2*j+1)*(2*k+1)/(4.0*bb))/(2*k+1);
    ws[OFF_WOUTQ+j] = (float)(2.0/bb * sin(PI_D*(2*j+1)/(4.0*bb)) * s);
  }
}

// ---------- init: LUT ----------
__global__ void k_lut(float* ws){
  int q = blockIdx.x*blockDim.x + threadIdx.x;
  if (q >= 1330) return;
  int l = 0; while (S2d(l+1) <= q) ++l;
  int loc = q - S2d(l), tl = 2*l+1;
  int mm = loc/tl, nn = loc%tl;
  ((int*)(ws+OFF_LUTA))[q] = 32*S2d(l) + mm*tl + nn;
  ((int*)(ws+OFF_LUTB))[q] = ((mm-l+9)*19 + (nn-l+9)) | ((tl*tl) << 9);
}

// ---------- init: Wigner-d tables ----------
__device__ double dfact(int n){ double r = 1.0; for (int i = 2; i <= n; ++i) r *= (double)i; return r; }

__device__ double dev_wigner(int l, int mp, int m, double beta){
  double ch = cos(0.5*beta), sh = sin(0.5*beta);
  int kmin = m - mp; if (kmin < 0) kmin = 0;
  int kmax = l + m; if (l - mp < kmax) kmax = l - mp;
  double pref = sqrt(dfact(l+mp)*dfact(l-mp)*dfact(l+m)*dfact(l-m));
  double sum = 0.0;
  for (int k = kmin; k <= kmax; ++k){
    double t = 1.0/(dfact(l+m-k)*dfact(k)*dfact(l-mp-k)*dfact(mp-m+k));
    if ((mp-m+k) & 1) t = -t;
    int ec = 2*l+m-mp-2*k, es = mp-m+2*k;
    double cp = 1.0; for (int e = 0; e < ec; ++e) cp *= ch;
    double sp = 1.0; for (int e = 0; e < es; ++e) sp *= sh;
    sum += t*cp*sp;
  }
  return pref*sum;
}

constexpr int N_DM0W = 60*256;
constexpr int N_DMID = 32*S2c(16);
constexpr int N_DOUT = 20*S2c(10);
constexpr int N_DEQ  = S2c(16);
constexpr int N_WIG  = N_DM0W + N_DMID + N_DOUT + N_DEQ;

__global__ void k_wigner(float* ws){
  int idx = blockIdx.x*blockDim.x + threadIdx.x;
  if (idx >= N_WIG) return;
  if (idx < N_DM0W){
    int l = 0; while (60*(l+1)*(l+1) <= idx) ++l;
    int rem = idx - 60*l*l, tl = 2*l+1;
    int p = rem/tl, mm = rem%tl;
    double beta = (p+0.5)*PI_D/60.0;
    ws[OFF_DM0W+idx] = (float)dev_wigner(l, mm-l, 0, beta) * ws[OFF_WIN+p];
    return;
  }
  idx -= N_DM0W;
  if (idx < N_DMID){
    int l = 0; while (32*S2d(l+1) <= idx) ++l;
    int rem = idx - 32*S2d(l), tl = 2*l+1;
    int q = rem % (tl*tl), p = rem/(tl*tl);
    int mm = q/tl, nn = q%tl;
    double beta = (p+0.5)*PI_D/32.0;
    ws[OFF_DMID+idx] = (float)dev_wigner(l, mm-l, nn-l, beta);
    return;
  }
  idx -= N_DMID;
  if (idx < N_DOUT){
    int l = 0; while (20*S2d(l+1) <= idx) ++l;
    int rem = idx - 20*S2d(l), tl = 2*l+1;
    int q = rem % (tl*tl), p = rem/(tl*tl);
    int mm = q/tl, nn = q%tl;
    double beta = (p+0.5)*PI_D/20.0;
    ws[OFF_DOUT+idx] = (float)dev_wigner(l, mm-l, nn-l, beta);
    return;
  }
  idx -= N_DOUT;
  {
    int l = 0; while (S2d(l+1) <= idx) ++l;
    int rem = idx - S2d(l), tl = 2*l+1;
    int mm = rem/tl, nn = rem%tl;
    ws[OFF_DEQ+idx] = (float)dev_wigner(l, mm-l, nn-l, 0.5*PI_D);
  }
}

// ---------- 1. projection ----------
__global__ void k_project(const float* __restrict__ x, float* ws){
  int t = blockIdx.x*blockDim.x + threadIdx.x;
  if (t >= NBATCH*NPTS) return;
  int b = t / NPTS, n = t % NPTS;
  const float* xb = x + (size_t)b*3*NPTS;
  float xx = xb[n], yy = xb[NPTS+n], zz = xb[2*NPTS+n];
  float r = sqrtf(xx*xx + yy*yy + zz*zz + 1e-12f);
  float ct = zz / r;
  ct = fminf(fmaxf(ct, -1.0f + 1e-7f), 1.0f - 1e-7f);
  float beta = acosf(ct);
  float alpha = atan2f(yy, xx);
  if (alpha < 0.0f) alpha += 2.0f*(float)PI_D;
  int jb = (int)((beta / (float)PI_D) * 60.0f);
  jb = jb < 0 ? 0 : (jb > 59 ? 59 : jb);
  int ja = (int)((alpha / (2.0f*(float)PI_D)) * 60.0f);
  ja = ja < 0 ? 0 : (ja > 59 ? 59 : ja);
  unsigned* img = (unsigned*)(ws + OFF_IMG) + (b*3600 + jb*60 + ja);
  atomicMax(img, __float_as_uint(r));
}

// ---------- 2. S2 DFT over alpha ----------
__global__ void k_s2dft(float* ws){
  int t = blockIdx.x*blockDim.x + threadIdx.x;
  if (t >= NBATCH*60*31) return;
  int b = t/(60*31), r = t%(60*31);
  int p = r/31, mi = r%31, m = mi - 15;
  const float* img = ws + OFF_IMG + (b*60 + p)*60;
  float sr = 0.f, si = 0.f;
  for (int a = 0; a < 60; ++a){
    int k = ((a*m) % 60 + 60) % 60;
    float c = cospif(k/30.0f), s = sinpif(k/30.0f);
    float v = img[a];
    sr += v*c; si -= v*s;
  }
  ws[OFF_XF + t*2]   = sr;
  ws[OFF_XF + t*2+1] = si;
}

// ---------- 3. xhat ----------
__global__ void k_xhat(float* ws){
  int t = blockIdx.x*blockDim.x + threadIdx.x;
  if (t >= NBATCH*256) return;
  int b = t/256, flat = t%256;
  int l = 0; while ((l+1)*(l+1) <= flat) ++l;
  int mm = flat - l*l, tl = 2*l+1;
  int mi = mm - l + 15;
  float sr = 0.f, si = 0.f;
  for (int p = 0; p < 60; ++p){
    float w = ws[OFF_DM0W + 60*l*l + p*tl + mm];
    sr += w * ws[OFF_XF + ((b*60+p)*31 + mi)*2];
    si += w * ws[OFF_XF + ((b*60+p)*31 + mi)*2 + 1];
  }
  ws[OFF_XHAT + t*2]   = sr;
  ws[OFF_XHAT + t*2+1] = si;
}

// ---------- 3b. Ws2 ----------
__global__ void k_ws2(float* ws, const float* __restrict__ w_s2, float scale1){
  int t = blockIdx.x*blockDim.x + threadIdx.x;
  if (t >= 100*31) return;
  int o = t/31, ni = t%31, n = ni - 15;
  float sr = 0.f, si = 0.f;
  for (int k = 0; k < 60; ++k){
    int kk = ((k*n) % 60 + 60) % 60;
    float c = cospif(kk/30.0f), s = sinpif(kk/30.0f);
    float v = w_s2[o*60 + k] * scale1;
    sr += v*c; si += v*s;
  }
  ws[OFF_WS2 + t*2]   = sr;
  ws[OFF_WS2 + t*2+1] = si;
}

// ---------- 4. fused zhat + SO(3) IFFT (b=16), Hermitian + radix-2 both dims ----------
__global__ __launch_bounds__(256) void k_so3ifft_mid(float* ws, const float* __restrict__ b_s2){
  int bid = blockIdx.x;
  int p = bid & 31, bo = bid >> 5;
  int o = bo % F1C, b = bo / F1C;
  __shared__ float xh[512], Cc[512], Fg[992], tmpS[1024];
  __shared__ float twr[32], twi[32], redA[4], redB[4];
  __shared__ int dbase[16];
  int tid = threadIdx.x;
  {
    int flat = tid;
    int l = 0; while ((l+1)*(l+1) <= flat) ++l;
    int mm = flat - l*l, tl = 2*l+1;
    xh[2*flat]   = ws[OFF_XHAT + (b*256+flat)*2];
    xh[2*flat+1] = ws[OFF_XHAT + (b*256+flat)*2+1];
    float deq0 = ws[OFF_DEQ + S2d(l) + mm*tl + l];
    int ni = mm - l + 15;
    float wr = ws[OFF_WS2 + (o*31+ni)*2], wi = ws[OFF_WS2 + (o*31+ni)*2+1];
    float f = (float)tl * deq0;
    Cc[2*flat] = f*wr; Cc[2*flat+1] = f*wi;
  }
  if (tid < 32){ twr[tid] = cospif(tid/16.0f); twi[tid] = sinpif(tid/16.0f); }
  if (tid < 16){ int l = tid, tl = 2*l+1; dbase[l] = OFF_DMID + 32*S2d(l) + p*tl*tl; }
  __syncthreads();
  // Fg[m][ni], m=0..15 (Hermitian)
  for (int q = tid; q < 496; q += 256){
    int m = q/31, ni = q%31, n = ni-15;
    int an = n < 0 ? -n : n;
    int lmin = m > an ? m : an;
    float ar = 0.f, ai = 0.f;
    for (int l = lmin; l < 16; ++l){
      int tl = 2*l+1;
      float d = ws[dbase[l] + (m+l)*tl + (n+l)];
      int fa = l*l + (m+l), fc = l*l + (n+l);
      float xr = xh[2*fa], xi = xh[2*fa+1];
      float cr = Cc[2*fc], ci = Cc[2*fc+1];
      ar += d*(xr*cr - xi*ci);
      ai += d*(xr*ci + xi*cr);
    }
    Fg[2*q] = ar; Fg[2*q+1] = ai;
  }
  __syncthreads();
  // alpha-pass radix-2: tmp[m][g], pairs (g, g+16). n even <=> ni odd.
  {
    int q = tid;                         // exactly 256 = 16m x 16g
    int m = q >> 4, g = q & 15;
    float Er=0.f, Ei=0.f, Or=0.f, Oi=0.f;
    int base = 2*m*31;
    for (int ni = 1; ni < 31; ni += 2){  // n even
      int k = ((ni-15)*g) & 31;
      float c = twr[k], s = twi[k];
      float fr = Fg[base+2*ni], fi = Fg[base+2*ni+1];
      Er += fr*c - fi*s; Ei += fr*s + fi*c;
    }
    for (int ni = 0; ni < 31; ni += 2){  // n odd
      int k = ((ni-15)*g) & 31;
      float c = twr[k], s = twi[k];
      float fr = Fg[base+2*ni], fi = Fg[base+2*ni+1];
      Or += fr*c - fi*s; Oi += fr*s + fi*c;
    }
    tmpS[2*(m*32+g)]      = Er+Or; tmpS[2*(m*32+g)+1]      = Ei+Oi;
    tmpS[2*(m*32+g+16)]   = Er-Or; tmpS[2*(m*32+g+16)+1]   = Ei-Oi;
  }
  __syncthreads();
  // gamma-pass radix-2: pairs (a, a+16) via m-parity
  float bsv = b_s2[o];
  float lsum = 0.f, lss = 0.f;
  float* z = ws + OFF_Z;
  size_t zb = ((size_t)(b*F1C+o)*32 + p)*1024;
  for (int q = tid; q < 512; q += 256){
    int a = q >> 5, g = q & 31;
    float E = 0.f, O = 0.f;
    for (int m = 2; m < 16; m += 2){
      int k = (m*a) & 31;
      E += tmpS[2*(m*32+g)]*twr[k] - tmpS[2*(m*32+g)+1]*twi[k];
    }
    for (int m = 1; m < 16; m += 2){
      int k = (m*a) & 31;
      O += tmpS[2*(m*32+g)]*twr[k] - tmpS[2*(m*32+g)+1]*twi[k];
    }
    float t0 = tmpS[2*g];
    float v1 = (t0 + 2.0f*(E+O))*(1.0f/1024.0f) + bsv;
    float v2 = (t0 + 2.0f*(E-O))*(1.0f/1024.0f) + bsv;
    z[zb + a*32 + g]        = v1;
    z[zb + (a+16)*32 + g]   = v2;
    lsum += v1+v2; lss += v1*v1+v2*v2;
  }
  for (int off = 32; off; off >>= 1){ lsum += __shfl_down(lsum, off); lss += __shfl_down(lss, off); }
  if ((tid & 63) == 0){ redA[tid>>6] = lsum; redB[tid>>6] = lss; }
  __syncthreads();
  if (tid == 0){
    atomicAdd(&ws[OFF_BN1 + o],       redA[0]+redA[1]+redA[2]+redA[3]);
    atomicAdd(&ws[OFF_BN1 + 100 + o], redB[0]+redB[1]+redB[2]+redB[3]);
  }
}

__global__ void k_bnfin1(float* ws, const float* __restrict__ g1, const float* __restrict__ be1){
  int t = threadIdx.x;
  if (t >= 100) return;
  const float invN = 1.0f/262144.0f;
  float mu = ws[OFF_BN1+t]*invN;
  float var = ws[OFF_BN1+100+t]*invN - mu*mu;
  float sA = rsqrtf(var + 1e-5f) * g1[t];
  ws[OFF_BN1AB+t]     = sA;
  ws[OFF_BN1AB+100+t] = be1[t] - mu*sA;
}

// ---------- 6a. BN1+ReLU + 2D DFT with radix-2 both dims ----------
__global__ __launch_bounds__(256) void k_so3fft_a(float* ws){
  int bid = blockIdx.x;
  int p = bid & 31, bo = bid >> 5;
  int o = bo % F1C;
  __shared__ float y[32*33];
  __shared__ float t1[1216];
  __shared__ float twr[32], twi[32];
  int tid = threadIdx.x;
  if (tid < 32){ twr[tid] = cospif(tid/16.0f); twi[tid] = sinpif(tid/16.0f); }
  float sA = ws[OFF_BN1AB+o], sB = ws[OFF_BN1AB+100+o];
  float* zp = ws + OFF_Z + (size_t)bid*1024;
  for (int q = tid; q < 1024; q += 256){
    float v = zp[q]*sA + sB;
    y[(q>>5)*33 + (q&31)] = v > 0.f ? v : 0.f;
  }
  __syncthreads();
  // butterfly over g: y[a][g] <- s, y[a][g+16] <- d
  for (int q = tid; q < 512; q += 256){
    int a = q >> 4, g = q & 15;
    float u = y[a*33+g], w = y[a*33+g+16];
    y[a*33+g] = u+w; y[a*33+g+16] = u-w;
  }
  __syncthreads();
  // t1[a][ni] = sum_g y e^{-2pi i g n/32}; n even uses s-half, n odd uses d-half
  for (int q = tid; q < 608; q += 256){
    int a = q/19, ni = q%19, n = ni-9;
    int off = (n & 1) ? 16 : 0;
    float sr = 0.f, si = 0.f;
    for (int g = 0; g < 16; ++g){
      int k = (g*n) & 31;
      float v = y[a*33+off+g];
      sr += v*twr[k]; si -= v*twi[k];
    }
    t1[2*q] = sr; t1[2*q+1] = si;
  }
  __syncthreads();
  // butterfly over a: t1[a] <- S, t1[a+16] <- D
  for (int q = tid; q < 304; q += 256){
    int a = q/19, ni = q%19;
    int i0 = 2*(a*19+ni), i1 = 2*((a+16)*19+ni);
    float xr=t1[i0], xi=t1[i0+1], yr=t1[i1], yi=t1[i1+1];
    t1[i0]=xr+yr; t1[i0+1]=xi+yi; t1[i1]=xr-yr; t1[i1+1]=xi-yi;
  }
  __syncthreads();
  // X2w rows m=0..9; m even uses S-half, m odd uses D-half; mirror m<0
  float wm = ws[OFF_WMID+p];
  for (int q = tid; q < 190; q += 256){
    int m = q/19, ni = q%19;
    int off = (m & 1) ? 16*19 : 0;
    float sr = 0.f, si = 0.f;
    for (int a = 0; a < 16; ++a){
      int k = (a*m) & 31;
      float c = twr[k], s = twi[k];
      float tr = t1[2*(off+a*19+ni)], ti = t1[2*(off+a*19+ni)+1];
      sr += tr*c + ti*s;
      si += ti*c - tr*s;
    }
    sr *= wm; si *= wm;
    int qf = (m+9)*19 + ni;
    zp[2*qf] = sr; zp[2*qf+1] = si;
    if (m > 0){
      int qm = (9-m)*19 + (18-ni);
      zp[2*qm] = sr; zp[2*qm+1] = -si;
    }
  }
}

// ---------- 6b. Wigner beta-projection, LDS-staged ----------
__global__ __launch_bounds__(256) void k_so3fft_b(float* ws){
  int bo = blockIdx.x;
  int tid = threadIdx.x;
  __shared__ float xw[722];
  const float* xwbase = ws + OFF_Z + (size_t)bo*32*1024;
  const int* lutA = (const int*)(ws + OFF_LUTA);
  const int* lutB = (const int*)(ws + OFF_LUTB);
  float accr[6], acci[6];
  int la[6], xi2[6], tl2v[6];
  #pragma unroll
  for (int j = 0; j < 6; ++j){
    accr[j] = 0.f; acci[j] = 0.f;
    int q = tid + 256*j;
    if (q < 1330){ la[j] = lutA[q]; int lb = lutB[q]; xi2[j] = 2*(lb & 511); tl2v[j] = lb >> 9; }
    else { la[j] = 0; xi2[j] = 0; tl2v[j] = 0; }
  }
  for (int pp = 0; pp < 32; ++pp){
    __syncthreads();
    for (int u = tid; u < 722; u += 256) xw[u] = xwbase[pp*1024 + u];
    __syncthreads();
    #pragma unroll
    for (int j = 0; j < 6; ++j){
      int q = tid + 256*j;
      if (q < 1330){
        float d = ws[OFF_DMID + la[j] + pp*tl2v[j]];
        accr[j] += d*xw[xi2[j]]; acci[j] += d*xw[xi2[j]+1];
      }
    }
  }
  #pragma unroll
  for (int j = 0; j < 6; ++j){
    int q = tid + 256*j;
    if (q < 1330){
      int base = OFF_XHAT2 + (bo*1330 + q)*2;
      ws[base]   = accr[j];
      ws[base+1] = acci[j];
    }
  }
}

// ---------- 7a. W[i][o][ni] ----------
__global__ void k_wconv(float* ws, const float* __restrict__ w_so3, float scale2){
  int t = blockIdx.x*blockDim.x + threadIdx.x;
  if (t >= 100*100*19) return;
  int ni = t % 19, io = t / 19;
  int n = ni - 9;
  float sr = 0.f, si = 0.f;
  for (int j = 0; j < 32; ++j){
    int k = (j*n) & 31;
    float c = cospif(k/16.0f), s = sinpif(k/16.0f);
    float v = w_so3[io*32 + j] * scale2;
    sr += v*c; si += v*s;
  }
  ws[OFF_WCONV + t*2]   = sr;
  ws[OFF_WCONV + t*2+1] = si;
}

// ---------- 7b. S = xhat2 . d_eq ----------
__global__ void k_S(float* ws){
  int t = blockIdx.x*blockDim.x + threadIdx.x;
  if (t >= NBATCH*100*1330) return;
  int q = t % 1330, bi = t / 1330;
  int l = 0; while (S2d(l+1) <= q) ++l;
  int loc = q - S2d(l), tl = 2*l+1;
  int mm = loc/tl, nn = loc%tl;
  float sr = 0.f, si = 0.f;
  int xbase = OFF_XHAT2 + (bi*1330 + S2d(l) + mm*tl)*2;
  int dbase = OFF_DEQ + S2d(l) + nn*tl;
  for (int k = 0; k < tl; ++k){
    float d = ws[dbase + k];
    sr += d * ws[xbase + 2*k];
    si += d * ws[xbase + 2*k + 1];
  }
  ws[OFF_SBUF + t*2]   = sr;
  ws[OFF_SBUF + t*2+1] = si;
}

// ---------- 7c. zhat2 = S . W over i ----------
__global__ void k_zhat2(float* ws){
  int t = blockIdx.x*blockDim.x + threadIdx.x;
  if (t >= NBATCH*100*1330) return;
  int q = t % 1330, bo = t / 1330;
  int o = bo % 100, b = bo / 100;
  int l = 0; while (S2d(l+1) <= q) ++l;
  int loc = q - S2d(l), tl = 2*l+1;
  int nn = loc % tl;
  int ni = nn - l + 9;
  float sr = 0.f, si = 0.f;
  for (int i = 0; i < 100; ++i){
    float Sr = ws[OFF_SBUF + ((b*100+i)*1330 + q)*2];
    float Si = ws[OFF_SBUF + ((b*100+i)*1330 + q)*2 + 1];
    float Wr = ws[OFF_WCONV + ((i*100+o)*19 + ni)*2];
    float Wi = ws[OFF_WCONV + ((i*100+o)*19 + ni)*2 + 1];
    sr += Sr*Wr - Si*Wi;
    si += Sr*Wi + Si*Wr;
  }
  ws[OFF_ZHAT2 + ((b*100+o)*1330 + q)*2]     = sr;
  ws[OFF_ZHAT2 + ((b*100+o)*1330 + q)*2 + 1] = si;
}

// ---------- 8. SO(3) IFFT (b=10), Hermitian + radix-2 both dims ----------
__global__ __launch_bounds__(256) void k_so3ifft_out(float* ws, const float* __restrict__ b_so3){
  int bid = blockIdx.x;
  int p = bid % 20, bo = bid / 20;
  int o = bo % F2C, b = bo / F2C;
  __shared__ float zh[2660], Fg[380], tmpS[400];
  __shared__ float twr[20], twi[20], redA[4], redB[4];
  int tid = threadIdx.x;
  for (int q = tid; q < 2660; q += 256) zh[q] = ws[OFF_ZHAT2 + (b*100+o)*2660 + q];
  if (tid < 20){ twr[tid] = cospif(tid/10.0f); twi[tid] = sinpif(tid/10.0f); }
  __syncthreads();
  // Fg[m][ni], m=0..9
  for (int q = tid; q < 190; q += 256){
    int m = q/19, ni = q%19, n = ni-9;
    int an = n < 0 ? -n : n;
    int lmin = m > an ? m : an;
    float ar = 0.f, ai = 0.f;
    for (int l = lmin; l < 10; ++l){
      int tl = 2*l+1;
      float d = ws[OFF_DOUT + 20*S2d(l) + (p*tl + (m+l))*tl + (n+l)] * (float)tl;
      int fz = S2d(l) + (m+l)*tl + (n+l);
      ar += d*zh[2*fz]; ai += d*zh[2*fz+1];
    }
    Fg[2*q] = ar; Fg[2*q+1] = ai;
  }
  __syncthreads();
  // alpha-pass radix-2: pairs (g, g+10); n even <=> ni odd
  for (int q = tid; q < 100; q += 256){
    int m = q/10, g = q%10;
    float Er=0.f, Ei=0.f, Or=0.f, Oi=0.f;
    int base = 2*m*19;
    for (int ni = 1; ni < 19; ni += 2){  // n even
      int n = ni-9;
      int k = ((n*g) % 20 + 20) % 20;
      float c = twr[k], s = twi[k];
      float fr = Fg[base+2*ni], fi = Fg[base+2*ni+1];
      Er += fr*c - fi*s; Ei += fr*s + fi*c;
    }
    for (int ni = 0; ni < 19; ni += 2){  // n odd
      int n = ni-9;
      int k = ((n*g) % 20 + 20) % 20;
      float c = twr[k], s = twi[k];
      float fr = Fg[base+2*ni], fi = Fg[base+2*ni+1];
      Or += fr*c - fi*s; Oi += fr*s + fi*c;
    }
    tmpS[2*(m*20+g)]      = Er+Or; tmpS[2*(m*20+g)+1]      = Ei+Oi;
    tmpS[2*(m*20+g+10)]   = Er-Or; tmpS[2*(m*20+g+10)+1]   = Ei-Oi;
  }
  __syncthreads();
  // gamma-pass radix-2: pairs (a, a+10) via m-parity
  float bsv = b_so3[o];
  float lsum = 0.f, lss = 0.f;
  float* z2 = ws + OFF_Z2;
  size_t zb = ((size_t)(b*100+o)*20 + p)*400;
  for (int q = tid; q < 200; q += 256){
    int a = q/20, g = q%20;
    float E = 0.f, O = 0.f;
    for (int m = 2; m < 10; m += 2){
      int k = (m*a) % 20;
      E += tmpS[2*(m*20+g)]*twr[k] - tmpS[2*(m*20+g)+1]*twi[k];
    }
    for (int m = 1; m < 10; m += 2){
      int k = (m*a) % 20;
      O += tmpS[2*(m*20+g)]*twr[k] - tmpS[2*(m*20+g)+1]*twi[k];
    }
    float t0 = tmpS[2*g];
    float v1 = (t0 + 2.0f*(E+O))*(1.0f/400.0f) + bsv;
    float v2 = (t0 + 2.0f*(E-O))*(1.0f/400.0f) + bsv;
    z2[zb + a*20 + g]       = v1;
    z2[zb + (a+10)*20 + g]  = v2;
    lsum += v1+v2; lss += v1*v1+v2*v2;
  }
  for (int off = 32; off; off >>= 1){ lsum += __shfl_down(lsum, off); lss += __shfl_down(lss, off); }
  if ((tid & 63) == 0){ redA[tid>>6] = lsum; redB[tid>>6] = lss; }
  __syncthreads();
  if (tid == 0){
    atomicAdd(&ws[OFF_BN2 + o],       redA[0]+redA[1]+redA[2]+redA[3]);
    atomicAdd(&ws[OFF_BN2 + 100 + o], redB[0]+redB[1]+redB[2]+redB[3]);
  }
}

__global__ void k_bnfin2(float* ws, const float* __restrict__ g2, const float* __restrict__ be2){
  int t = threadIdx.x;
  if (t >= 100) return;
  const float invN = 1.0f/64000.0f;
  float mu = ws[OFF_BN2+t]*invN;
  float var = ws[OFF_BN2+100+t]*invN - mu*mu;
  float sA = rsqrtf(var + 1e-5f) * g2[t];
  ws[OFF_BN2AB+t]     = sA;
  ws[OFF_BN2AB+100+t] = be2[t] - mu*sA;
}

// ---------- 9. final pooling ----------
__global__ __launch_bounds__(256) void k_final(float* ws, float* __restrict__ out){
  int bid = blockIdx.x;
  int c = bid % 100, b = bid / 100;
  int tid = threadIdx.x;
  float sA = ws[OFF_BN2AB+c], sB = ws[OFF_BN2AB+100+c];
  const float* z2 = ws + OFF_Z2 + (size_t)(b*100+c)*8000;
  float lsum = 0.f;
  for (int q = tid; q < 8000; q += 256){
    int p = q / 400;
    float v = z2[q]*sA + sB;
    v = v > 0.f ? v : 0.f;
    lsum += v * ws[OFF_WOUTQ + p];
  }
  for (int off = 32; off; off >>= 1) lsum += __shfl_down(lsum, off);
  __shared__ float red[4];
  if ((tid & 63) == 0) red[tid>>6] = lsum;
  __syncthreads();
  if (tid == 0) out[b*100 + c] = red[0]+red[1]+red[2]+red[3];
}

extern "C" void kernel_launch(void* const* d_in, const int* in_sizes, int n_in,
                              void* d_out, int out_size, void* d_ws, size_t ws_size,
                              hipStream_t stream){
  const float* x      = (const float*)d_in[0];
  const float* w_s2   = (const float*)d_in[1];
  const float* b_s2   = (const float*)d_in[2];
  const float* g1     = (const float*)d_in[3];
  const float* be1    = (const float*)d_in[4];
  const float* w_so3  = (const float*)d_in[5];
  const float* b_so3  = (const float*)d_in[6];
  const float* g2     = (const float*)d_in[7];
  const float* be2    = (const float*)d_in[8];
  float* ws  = (float*)d_ws;
  float* out = (float*)d_out;

  hipMemsetAsync(ws + OFF_IMG, 0, NBATCH*3600*sizeof(float), stream);
  hipMemsetAsync(ws + OFF_BN1, 0, 200*sizeof(float), stream);
  hipMemsetAsync(ws + OFF_BN2, 0, 200*sizeof(float), stream);

  k_quad<<<1, 128, 0, stream>>>(ws);
  k_lut<<<6, 256, 0, stream>>>(ws);
  k_wigner<<<(N_WIG + 255)/256, 256, 0, stream>>>(ws);
  k_project<<<(NBATCH*NPTS + 255)/256, 256, 0, stream>>>(x, ws);
  k_s2dft<<<(NBATCH*60*31 + 255)/256, 256, 0, stream>>>(ws);
  k_xhat<<<(NBATCH*256 + 255)/256, 256, 0, stream>>>(ws);
  float scale1 = (float)(1.0/sqrt(60.0*1.0*65536.0/900.0));
  k_ws2<<<(100*31 + 255)/256, 256, 0, stream>>>(ws, w_s2, scale1);
  k_so3ifft_mid<<<NBATCH*F1C*32, 256, 0, stream>>>(ws, b_s2);
  k_bnfin1<<<1, 128, 0, stream>>>(ws, g1, be1);
  k_so3fft_a<<<NBATCH*F1C*32, 256, 0, stream>>>(ws);
  k_so3fft_b<<<NBATCH*F1C, 256, 0, stream>>>(ws);
  float scale2 = (float)(1.0/sqrt(32.0*100.0*1000.0/4096.0));
  k_wconv<<<(100*100*19 + 255)/256, 256, 0, stream>>>(ws, w_so3, scale2);
  k_S<<<(NBATCH*100*1330 + 255)/256, 256, 0, stream>>>(ws);
  k_zhat2<<<(NBATCH*100*1330 + 255)/256, 256, 0, stream>>>(ws);
  k_so3ifft_out<<<NBATCH*F2C*20, 256, 0, stream>>>(ws, b_so3);
  k_bnfin2<<<1, 128, 0, stream>>>(ws, g2, be2);
  k_final<<<NBATCH*100, 256, 0, stream>>>(ws, out);
}